// Round 1
// baseline (47127.954 us; speedup 1.0000x reference)
//
#include <hip/hip_runtime.h>
#include <cmath>

// ResLSTM+CRF on MI355X, fp32 vector-ALU implementation.
// Activations stored k-chunked, batch-inner: float index (k>>2)*256 + lane*4 + (k&3)
// so a lane reads float4 (4 consecutive k) per load. Weights read via scalar loads.

namespace {
constexpr int SS = 512;     // seq len
constexpr int BB = 64;      // batch
constexpr int EE = 256;     // embed dim
constexpr int HHd = 256;    // half hidden (bi-lstm)
constexpr int HD = 512;     // hidden (stack)
constexpr int NTAG = 22;
constexpr int TSTART = 20;
constexpr int TSTOP = 21;

// ws offsets (in floats)
constexpr size_t OFF_BI    = 0;                                   // [512][512][64] chunked
constexpr size_t OFF_H1H   = OFF_BI    + (size_t)SS * HD * BB;    // [513][512][64] chunked
constexpr size_t OFF_XT    = OFF_H1H   + (size_t)(SS + 1) * HD * BB; // [512][256][64] chunked
constexpr size_t OFF_FEATS = OFF_XT    + (size_t)SS * EE * BB;    // [512][22][64] plain
constexpr size_t OFF_H0R   = OFF_FEATS + (size_t)SS * NTAG * BB;  // [2][512][64] chunked ring
constexpr size_t OFF_HF    = OFF_H0R   + 2 * (size_t)HD * BB;     // [2][256][64] chunked dbl-buf
constexpr size_t OFF_HB    = OFF_HF    + 2 * (size_t)HHd * BB;
constexpr size_t OFF_CF    = OFF_HB    + 2 * (size_t)HHd * BB;    // [256][64] plain
constexpr size_t OFF_CB    = OFF_CF    + (size_t)HHd * BB;
constexpr size_t OFF_C0    = OFF_CB    + (size_t)HHd * BB;        // [512][64] plain
constexpr size_t OFF_C1    = OFF_C0    + (size_t)HD * BB;
constexpr size_t OFF_BAR   = OFF_C1    + (size_t)HD * BB;         // 4 ints of barrier state
}

__device__ __forceinline__ int cidx(int k, int lane) {
  return ((k >> 2) << 8) + (lane << 2) + (k & 3);
}

// Device-wide barrier: monotonic counter + epoch flag, agent scope.
// Requires all blocks co-resident (grid=256 small blocks on 256 CUs -> guaranteed).
__device__ __forceinline__ void gbar(int* cnt, int* flag, int nblk, int epoch) {
  __syncthreads();
  if (threadIdx.x == 0) {
    __threadfence();
    int prev = __hip_atomic_fetch_add(cnt, 1, __ATOMIC_RELAXED, __HIP_MEMORY_SCOPE_AGENT);
    if (prev == epoch * nblk + (nblk - 1)) {
      __hip_atomic_store(flag, epoch + 1, __ATOMIC_RELAXED, __HIP_MEMORY_SCOPE_AGENT);
    } else {
      while (__hip_atomic_load(flag, __ATOMIC_RELAXED, __HIP_MEMORY_SCOPE_AGENT) <= epoch) {
        __builtin_amdgcn_s_sleep(2);
      }
    }
    __threadfence();
  }
  __syncthreads();
}

__device__ __forceinline__ float sigm(float x) { return 1.f / (1.f + expf(-x)); }

// K0: gather embeddings, transpose to chunked [t][e-chunk][lane][4]
__global__ __launch_bounds__(256) void k0(const int* __restrict__ sent,
                                          const float* __restrict__ emb,
                                          float* __restrict__ xT) {
  const int t = blockIdx.x;
  const int lane = threadIdx.x & 63;
  const int w = __builtin_amdgcn_readfirstlane(threadIdx.x >> 6); // 0..3
  __shared__ float tile[64][65];
  __shared__ int rows[64];
  if (threadIdx.x < 64) rows[threadIdx.x] = sent[(size_t)threadIdx.x * SS + t];
  __syncthreads();
  float4* xT4 = (float4*)xT;
  for (int e0 = 0; e0 < EE; e0 += 64) {
    for (int bb = 0; bb < 16; ++bb) {
      int b = bb * 4 + w;
      tile[b][lane] = emb[(size_t)rows[b] * EE + e0 + lane];
    }
    __syncthreads();
    for (int r = 0; r < 4; ++r) {
      int ecl = w * 4 + r;                 // 0..15 local float4-chunk
      int ec = (e0 >> 2) + ecl;            // global chunk 0..63
      float4 v = make_float4(tile[lane][ecl * 4 + 0], tile[lane][ecl * 4 + 1],
                             tile[lane][ecl * 4 + 2], tile[lane][ecl * 4 + 3]);
      xT4[((size_t)t * 64 + ec) * 64 + lane] = v;
    }
    __syncthreads();
  }
}

// dot over chunked activation: 4 gate accumulators
__device__ __forceinline__ void dot4(const float4* __restrict__ p,
                                     const float* __restrict__ w0, const float* __restrict__ w1,
                                     const float* __restrict__ w2, const float* __restrict__ w3,
                                     int KC, float& a0, float& a1, float& a2, float& a3) {
#pragma unroll 4
  for (int c = 0; c < KC; ++c) {
    float4 h = p[c * 64];
    int k = c * 4;
    a0 = fmaf(h.x, w0[k], a0); a0 = fmaf(h.y, w0[k + 1], a0);
    a0 = fmaf(h.z, w0[k + 2], a0); a0 = fmaf(h.w, w0[k + 3], a0);
    a1 = fmaf(h.x, w1[k], a1); a1 = fmaf(h.y, w1[k + 1], a1);
    a1 = fmaf(h.z, w1[k + 2], a1); a1 = fmaf(h.w, w1[k + 3], a1);
    a2 = fmaf(h.x, w2[k], a2); a2 = fmaf(h.y, w2[k + 1], a2);
    a2 = fmaf(h.z, w2[k + 2], a2); a2 = fmaf(h.w, w2[k + 3], a2);
    a3 = fmaf(h.x, w3[k], a3); a3 = fmaf(h.y, w3[k + 1], a3);
    a3 = fmaf(h.z, w3[k + 2], a3); a3 = fmaf(h.w, w3[k + 3], a3);
  }
}

struct K2A {
  const float* xT; float* bi;
  const float* wih_f; const float* whh_f; const float* b_f;
  const float* wih_b; const float* whh_b; const float* b_b;
  const float* h10; const float* c10; const int* lengths;
  float* hf; float* hb; float* cf; float* cb;
  int* cnt; int* flag;
};

// K2: BiLSTM, both directions concurrently. 256 blocks x 256 thr.
// gw = bid*4+w; unit = gw>>1 (0..511: <256 fwd, >=256 bwd); parity 0 = x-part, 1 = h-part.
__global__ __launch_bounds__(256) void k2(K2A a) {
  const int lane = threadIdx.x & 63;
  const int w = __builtin_amdgcn_readfirstlane(threadIdx.x >> 6);
  const int gw = (int)blockIdx.x * 4 + w;
  const int unit = gw >> 1;
  const int par = gw & 1;
  const int d = unit >> 8;
  const int u = unit & 255;
  const float* Wg = par ? (d ? a.whh_b : a.whh_f) : (d ? a.wih_b : a.wih_f);
  const float* bias = d ? a.b_b : a.b_f;
  float* hbuf = d ? a.hb : a.hf;
  float* cT = d ? a.cb : a.cf;
  const int len = a.lengths[lane];
  const float* w0 = Wg + (size_t)(0 * HHd + u) * 256;
  const float* w1 = Wg + (size_t)(1 * HHd + u) * 256;
  const float* w2 = Wg + (size_t)(2 * HHd + u) * 256;
  const float* w3 = Wg + (size_t)(3 * HHd + u) * 256;
  __shared__ float part[4][4][64];
  if (par == 0) {
    hbuf[cidx(u, lane)] = a.h10[d * 256 + u];
    cT[u * 64 + lane] = a.c10[d * 256 + u];
  }
  int ep = 0;
  gbar(a.cnt, a.flag, 256, ep++);
  int buf = 0;
  for (int step = 0; step < SS; ++step) {
    const int t = d ? (SS - 1 - step) : step;
    const float* act = par ? (hbuf + (size_t)buf * (HHd * 64))
                           : (a.xT + (size_t)t * (EE * 64));
    const float4* p = (const float4*)act + lane;
    float a0 = 0.f, a1 = 0.f, a2 = 0.f, a3 = 0.f;
    dot4(p, w0, w1, w2, w3, 64, a0, a1, a2, a3);
    part[w][0][lane] = a0; part[w][1][lane] = a1;
    part[w][2][lane] = a2; part[w][3][lane] = a3;
    __syncthreads();
    if (par == 0) {
      float gi = part[w][0][lane] + part[w + 1][0][lane] + bias[u];
      float gf = part[w][1][lane] + part[w + 1][1][lane] + bias[256 + u];
      float gg = part[w][2][lane] + part[w + 1][2][lane] + bias[512 + u];
      float go = part[w][3][lane] + part[w + 1][3][lane] + bias[768 + u];
      float c_old = cT[u * 64 + lane];
      float h_old = hbuf[(size_t)buf * (HHd * 64) + cidx(u, lane)];
      float i_ = sigm(gi), f_ = sigm(gf), o_ = sigm(go);
      float gn = tanhf(gg);
      float c2 = f_ * c_old + i_ * gn;
      float h2 = o_ * tanhf(c2);
      const bool m = (t < len);
      hbuf[(size_t)(buf ^ 1) * (HHd * 64) + cidx(u, lane)] = m ? h2 : h_old;
      cT[u * 64 + lane] = m ? c2 : c_old;
      a.bi[(size_t)t * (HD * 64) + cidx(d * 256 + u, lane)] = m ? h2 : 0.f;
    }
    buf ^= 1;
    gbar(a.cnt, a.flag, 256, ep++);  // leading __syncthreads protects part[] reuse
  }
}

struct K4A {
  const float* bi; float* h0r; float* h1h;
  const float* wihs; const float* whhs; const float* bs;
  const float* h20; const float* c20;
  float* c0T; float* c1T;
  int* cnt; int* flag;
};

// K4: 2-layer stack LSTM, software-pipelined: super-step t computes
// layer0(t) and layer1(t-1). 256 blocks x 512 thr. Blocks <128 = layer0.
__global__ __launch_bounds__(512) void k4(K4A a) {
  const int lane = threadIdx.x & 63;
  const int w = __builtin_amdgcn_readfirstlane(threadIdx.x >> 6);  // 0..7
  const int layer = (int)blockIdx.x >> 7;
  const int lb = (int)blockIdx.x & 127;
  const int unit = lb * 4 + (w >> 1);  // 0..511
  const int par = w & 1;               // 0 = x-part, 1 = h-part
  const size_t woff = (size_t)layer * (2048 * 512);
  const float* Wg = (par ? a.whhs : a.wihs) + woff;
  const float* w0 = Wg + (size_t)(0 * HD + unit) * HD;
  const float* w1 = Wg + (size_t)(1 * HD + unit) * HD;
  const float* w2 = Wg + (size_t)(2 * HD + unit) * HD;
  const float* w3 = Wg + (size_t)(3 * HD + unit) * HD;
  float* cT = layer ? a.c1T : a.c0T;
  __shared__ float part[8][4][64];
  if (par == 0) {
    if (layer == 0) a.h0r[cidx(unit, lane)] = a.h20[unit];            // ring slot 0
    else            a.h1h[cidx(unit, lane)] = a.h20[512 + unit];      // slot 0
    cT[unit * 64 + lane] = layer ? a.c20[512 + unit] : a.c20[unit];
  }
  int ep = 0;
  gbar(a.cnt, a.flag, 256, ep++);
  for (int t = 0; t <= SS; ++t) {
    const bool active = (layer == 0) ? (t < SS) : (t >= 1);
    float a0 = 0.f, a1 = 0.f, a2 = 0.f, a3 = 0.f;
    if (active) {
      const float* act;
      if (layer == 0)
        act = par ? (a.h0r + (size_t)(t & 1) * (HD * 64))    // h0(t-1)
                  : (a.bi + (size_t)t * (HD * 64));          // bi[t]
      else
        act = par ? (a.h1h + (size_t)(t - 1) * (HD * 64))    // h1(t-2)
                  : (a.h0r + (size_t)(t & 1) * (HD * 64));   // h0(t-1)
      const float4* p = (const float4*)act + lane;
      dot4(p, w0, w1, w2, w3, 128, a0, a1, a2, a3);
    }
    part[w][0][lane] = a0; part[w][1][lane] = a1;
    part[w][2][lane] = a2; part[w][3][lane] = a3;
    __syncthreads();
    if (active && par == 0) {
      const float* bs = a.bs + (size_t)layer * 2048;
      float gi = part[w][0][lane] + part[w + 1][0][lane] + bs[unit];
      float gf = part[w][1][lane] + part[w + 1][1][lane] + bs[512 + unit];
      float gg = part[w][2][lane] + part[w + 1][2][lane] + bs[1024 + unit];
      float go = part[w][3][lane] + part[w + 1][3][lane] + bs[1536 + unit];
      float c_old = cT[unit * 64 + lane];
      float i_ = sigm(gi), f_ = sigm(gf), o_ = sigm(go);
      float gn = tanhf(gg);
      float c2 = f_ * c_old + i_ * gn;
      float h2 = o_ * tanhf(c2);
      if (layer == 0) a.h0r[(size_t)((t + 1) & 1) * (HD * 64) + cidx(unit, lane)] = h2;
      else            a.h1h[(size_t)t * (HD * 64) + cidx(unit, lane)] = h2;  // h1(t-1)
      cT[unit * 64 + lane] = c2;
    }
    gbar(a.cnt, a.flag, 256, ep++);
  }
}

// K4b: feats[t][j][b] = h1(t) . W_tag[j] + b_tag[j]
__global__ __launch_bounds__(256) void k4b(const float* __restrict__ h1h,
                                           const float* __restrict__ Wtag,
                                           const float* __restrict__ btag,
                                           float* __restrict__ feats) {
  const int t = blockIdx.x;
  const int lane = threadIdx.x & 63;
  const int w = __builtin_amdgcn_readfirstlane(threadIdx.x >> 6);
  const int j0 = w * 6;
  const float4* p = (const float4*)(h1h + (size_t)(t + 1) * (HD * 64)) + lane;
  const float* r[6];
  float acc[6];
#pragma unroll
  for (int jj = 0; jj < 6; ++jj) {
    int j = j0 + jj; if (j > 21) j = 21;
    r[jj] = Wtag + (size_t)j * HD;
    acc[jj] = btag[j];
  }
#pragma unroll 2
  for (int c = 0; c < 128; ++c) {
    float4 h = p[c * 64];
    int k = c * 4;
#pragma unroll
    for (int jj = 0; jj < 6; ++jj) {
      acc[jj] = fmaf(h.x, r[jj][k], acc[jj]);
      acc[jj] = fmaf(h.y, r[jj][k + 1], acc[jj]);
      acc[jj] = fmaf(h.z, r[jj][k + 2], acc[jj]);
      acc[jj] = fmaf(h.w, r[jj][k + 3], acc[jj]);
    }
  }
#pragma unroll
  for (int jj = 0; jj < 6; ++jj) {
    int j = j0 + jj;
    if (j < NTAG) feats[((size_t)t * NTAG + j) * 64 + lane] = acc[jj];
  }
}

// K5: Viterbi decode, one block per batch element, backpointers in LDS.
__global__ __launch_bounds__(64) void k5(const float* __restrict__ feats,
                                         const float* __restrict__ trans,
                                         const int* __restrict__ lengths,
                                         float* __restrict__ out) {
  const int b = blockIdx.x;
  const int j = threadIdx.x;
  __shared__ float tr[NTAG * NTAG];
  __shared__ float sc[NTAG];
  __shared__ float term[NTAG];
  __shared__ unsigned char bp[SS - 1][NTAG];
  for (int i = j; i < NTAG * NTAG; i += 64) tr[i] = trans[i];
  const int len = lengths[b];
  float score = 0.f;
  __syncthreads();
  if (j < NTAG) {
    score = feats[(size_t)j * 64 + b] + tr[j * NTAG + TSTART];
    sc[j] = score;
  }
  __syncthreads();
  for (int t = 1; t < len; ++t) {
    float best = -3.4e38f; int bi_ = 0;
    if (j < NTAG) {
#pragma unroll
      for (int i = 0; i < NTAG; ++i) {
        float c = sc[i] + tr[j * NTAG + i];
        if (c > best) { best = c; bi_ = i; }   // strict > keeps first max (argmax semantics)
      }
      score = best + feats[((size_t)t * NTAG + j) * 64 + b];
      bp[t - 1][j] = (unsigned char)bi_;
    }
    __syncthreads();
    if (j < NTAG) sc[j] = score;
    __syncthreads();
  }
  if (j < NTAG) term[j] = score + tr[TSTOP * NTAG + j];
  __syncthreads();
  if (j == 0) {
    float bs = term[0]; int bt = 0;
    for (int i = 1; i < NTAG; ++i) if (term[i] > bs) { bs = term[i]; bt = i; }
    out[b] = bs;
    int tag = bt;
    for (int t = SS - 1; t >= 1; --t) {
      out[64 + (size_t)b * SS + t] = (float)tag;
      if (t < len) tag = bp[t - 1][tag];       // masked steps: identity backpointer
    }
    out[64 + (size_t)b * SS + 0] = (float)tag;
  }
}

extern "C" void kernel_launch(void* const* d_in, const int* in_sizes, int n_in,
                              void* d_out, int out_size, void* d_ws, size_t ws_size,
                              hipStream_t stream) {
  const int* sentence = (const int*)d_in[0];
  const int* lengths  = (const int*)d_in[1];
  const float* emb    = (const float*)d_in[2];
  const float* wih_f  = (const float*)d_in[3];
  const float* whh_f  = (const float*)d_in[4];
  const float* b_f    = (const float*)d_in[5];
  const float* wih_b  = (const float*)d_in[6];
  const float* whh_b  = (const float*)d_in[7];
  const float* b_b    = (const float*)d_in[8];
  const float* h10    = (const float*)d_in[9];
  const float* c10    = (const float*)d_in[10];
  const float* wihs   = (const float*)d_in[11];
  const float* whhs   = (const float*)d_in[12];
  const float* bs     = (const float*)d_in[13];
  const float* h20    = (const float*)d_in[14];
  const float* c20    = (const float*)d_in[15];
  const float* Wtag   = (const float*)d_in[16];
  const float* btag   = (const float*)d_in[17];
  const float* trans  = (const float*)d_in[18];
  float* ws = (float*)d_ws;
  float* out = (float*)d_out;

  // zero barrier state (ws is poisoned 0xAA before every call)
  hipMemsetAsync((void*)(ws + OFF_BAR), 0, 4 * sizeof(int), stream);

  k0<<<dim3(SS), dim3(256), 0, stream>>>(sentence, emb, ws + OFF_XT);

  K2A a2{ws + OFF_XT, ws + OFF_BI, wih_f, whh_f, b_f, wih_b, whh_b, b_b,
         h10, c10, lengths,
         ws + OFF_HF, ws + OFF_HB, ws + OFF_CF, ws + OFF_CB,
         (int*)(ws + OFF_BAR) + 0, (int*)(ws + OFF_BAR) + 1};
  k2<<<dim3(256), dim3(256), 0, stream>>>(a2);

  K4A a4{ws + OFF_BI, ws + OFF_H0R, ws + OFF_H1H, wihs, whhs, bs, h20, c20,
         ws + OFF_C0, ws + OFF_C1,
         (int*)(ws + OFF_BAR) + 2, (int*)(ws + OFF_BAR) + 3};
  k4<<<dim3(256), dim3(512), 0, stream>>>(a4);

  k4b<<<dim3(SS), dim3(256), 0, stream>>>(ws + OFF_H1H, Wtag, btag, ws + OFF_FEATS);
  k5<<<dim3(BB), dim3(64), 0, stream>>>(ws + OFF_FEATS, trans, lengths, out);
}

// Round 2
// 42855.841 us; speedup vs baseline: 1.0997x; 1.0997x over previous
//
#include <hip/hip_runtime.h>
#include <cmath>

// ResLSTM+CRF on MI355X, fp32 vector-ALU implementation.
// Activations stored k-chunked, batch-inner: float index (k>>2)*256 + lane*4 + (k&3)
// so a lane reads float4 (4 consecutive k) per load. Weights read via scalar loads.
// R2: contended-atomic barrier -> symmetric flag-array barrier (no RMW contention);
//     k2 split into per-direction barrier groups; dot4 unroll 8.

namespace {
constexpr int SS = 512;     // seq len
constexpr int BB = 64;      // batch
constexpr int EE = 256;     // embed dim
constexpr int HHd = 256;    // half hidden (bi-lstm)
constexpr int HD = 512;     // hidden (stack)
constexpr int NTAG = 22;
constexpr int TSTART = 20;
constexpr int TSTOP = 21;

// ws offsets (in floats)
constexpr size_t OFF_BI    = 0;                                   // [512][512][64] chunked
constexpr size_t OFF_H1H   = OFF_BI    + (size_t)SS * HD * BB;    // [513][512][64] chunked
constexpr size_t OFF_XT    = OFF_H1H   + (size_t)(SS + 1) * HD * BB; // [512][256][64] chunked
constexpr size_t OFF_FEATS = OFF_XT    + (size_t)SS * EE * BB;    // [512][22][64] plain
constexpr size_t OFF_H0R   = OFF_FEATS + (size_t)SS * NTAG * BB;  // [2][512][64] chunked ring
constexpr size_t OFF_HF    = OFF_H0R   + 2 * (size_t)HD * BB;     // [2][256][64] chunked dbl-buf
constexpr size_t OFF_HB    = OFF_HF    + 2 * (size_t)HHd * BB;
constexpr size_t OFF_CF    = OFF_HB    + 2 * (size_t)HHd * BB;    // [256][64] plain
constexpr size_t OFF_CB    = OFF_CF    + (size_t)HHd * BB;
constexpr size_t OFF_C0    = OFF_CB    + (size_t)HHd * BB;        // [512][64] plain
constexpr size_t OFF_C1    = OFF_C0    + (size_t)HD * BB;
constexpr size_t OFF_BAR   = OFF_C1    + (size_t)HD * BB;         // flag arrays (ints)
// layout of barrier ints: [0..127] k2 fwd, [128..255] k2 bwd, [256..511] k4
}

__device__ __forceinline__ int cidx(int k, int lane) {
  return ((k >> 2) << 8) + (lane << 2) + (k & 3);
}

// Symmetric flag-array device barrier. Each block stores epoch+1 into its own
// flag word (release); every block's wave-0 polls all NBLK flags in parallel
// (64 lanes x NBLK/64 words). No atomic RMW -> no serialization on one line.
// Requires all participating blocks co-resident (1 block/CU grids).
template <int NBLK>
__device__ __forceinline__ void gbar2(int* flags, int bid, int epoch) {
  __syncthreads();
  const int tid = threadIdx.x;
  if (tid == 0) {
    __threadfence();  // release: make this block's writes visible first
    __hip_atomic_store(flags + bid, epoch + 1, __ATOMIC_RELAXED, __HIP_MEMORY_SCOPE_AGENT);
  }
  if (tid < 64) {
    constexpr int PER = NBLK / 64;
    bool ok;
    do {
      ok = true;
#pragma unroll
      for (int i = 0; i < PER; ++i) {
        ok = ok && (__hip_atomic_load(flags + tid * PER + i, __ATOMIC_RELAXED,
                                      __HIP_MEMORY_SCOPE_AGENT) > epoch);
      }
    } while (__any(!ok));
    if (tid == 0) __threadfence();  // acquire (fence invalidates per-CU L1)
  }
  __syncthreads();
}

__device__ __forceinline__ float sigm(float x) { return 1.f / (1.f + expf(-x)); }

// K0: gather embeddings, transpose to chunked [t][e-chunk][lane][4]
__global__ __launch_bounds__(256) void k0(const int* __restrict__ sent,
                                          const float* __restrict__ emb,
                                          float* __restrict__ xT) {
  const int t = blockIdx.x;
  const int lane = threadIdx.x & 63;
  const int w = __builtin_amdgcn_readfirstlane(threadIdx.x >> 6); // 0..3
  __shared__ float tile[64][65];
  __shared__ int rows[64];
  if (threadIdx.x < 64) rows[threadIdx.x] = sent[(size_t)threadIdx.x * SS + t];
  __syncthreads();
  float4* xT4 = (float4*)xT;
  for (int e0 = 0; e0 < EE; e0 += 64) {
    for (int bb = 0; bb < 16; ++bb) {
      int b = bb * 4 + w;
      tile[b][lane] = emb[(size_t)rows[b] * EE + e0 + lane];
    }
    __syncthreads();
    for (int r = 0; r < 4; ++r) {
      int ecl = w * 4 + r;                 // 0..15 local float4-chunk
      int ec = (e0 >> 2) + ecl;            // global chunk 0..63
      float4 v = make_float4(tile[lane][ecl * 4 + 0], tile[lane][ecl * 4 + 1],
                             tile[lane][ecl * 4 + 2], tile[lane][ecl * 4 + 3]);
      xT4[((size_t)t * 64 + ec) * 64 + lane] = v;
    }
    __syncthreads();
  }
}

// dot over chunked activation: 4 gate accumulators
__device__ __forceinline__ void dot4(const float4* __restrict__ p,
                                     const float* __restrict__ w0, const float* __restrict__ w1,
                                     const float* __restrict__ w2, const float* __restrict__ w3,
                                     int KC, float& a0, float& a1, float& a2, float& a3) {
#pragma unroll 8
  for (int c = 0; c < KC; ++c) {
    float4 h = p[c * 64];
    int k = c * 4;
    a0 = fmaf(h.x, w0[k], a0); a0 = fmaf(h.y, w0[k + 1], a0);
    a0 = fmaf(h.z, w0[k + 2], a0); a0 = fmaf(h.w, w0[k + 3], a0);
    a1 = fmaf(h.x, w1[k], a1); a1 = fmaf(h.y, w1[k + 1], a1);
    a1 = fmaf(h.z, w1[k + 2], a1); a1 = fmaf(h.w, w1[k + 3], a1);
    a2 = fmaf(h.x, w2[k], a2); a2 = fmaf(h.y, w2[k + 1], a2);
    a2 = fmaf(h.z, w2[k + 2], a2); a2 = fmaf(h.w, w2[k + 3], a2);
    a3 = fmaf(h.x, w3[k], a3); a3 = fmaf(h.y, w3[k + 1], a3);
    a3 = fmaf(h.z, w3[k + 2], a3); a3 = fmaf(h.w, w3[k + 3], a3);
  }
}

struct K2A {
  const float* xT; float* bi;
  const float* wih_f; const float* whh_f; const float* b_f;
  const float* wih_b; const float* whh_b; const float* b_b;
  const float* h10; const float* c10; const int* lengths;
  float* hf; float* hb; float* cf; float* cb;
  int* flags;   // [0..127] fwd group, [128..255] bwd group
};

// K2: BiLSTM, both directions concurrently. 256 blocks x 256 thr.
// gw = bid*4+w; unit = gw>>1 (0..511: <256 fwd, >=256 bwd); parity 0 = x-part, 1 = h-part.
// Blocks 0..127 are entirely fwd, 128..255 entirely bwd -> independent barrier groups.
__global__ __launch_bounds__(256) void k2(K2A a) {
  const int lane = threadIdx.x & 63;
  const int w = __builtin_amdgcn_readfirstlane(threadIdx.x >> 6);
  const int gw = (int)blockIdx.x * 4 + w;
  const int unit = gw >> 1;
  const int par = gw & 1;
  const int d = unit >> 8;
  const int u = unit & 255;
  const int grp = (int)blockIdx.x >> 7;          // == d for all waves in block
  const int bid = (int)blockIdx.x & 127;
  int* flags = a.flags + grp * 128;
  const float* Wg = par ? (d ? a.whh_b : a.whh_f) : (d ? a.wih_b : a.wih_f);
  const float* bias = d ? a.b_b : a.b_f;
  float* hbuf = d ? a.hb : a.hf;
  float* cT = d ? a.cb : a.cf;
  const int len = a.lengths[lane];
  const float* w0 = Wg + (size_t)(0 * HHd + u) * 256;
  const float* w1 = Wg + (size_t)(1 * HHd + u) * 256;
  const float* w2 = Wg + (size_t)(2 * HHd + u) * 256;
  const float* w3 = Wg + (size_t)(3 * HHd + u) * 256;
  __shared__ float part[4][4][64];
  if (par == 0) {
    hbuf[cidx(u, lane)] = a.h10[d * 256 + u];
    cT[u * 64 + lane] = a.c10[d * 256 + u];
  }
  int ep = 0;
  gbar2<128>(flags, bid, ep); ep++;
  int buf = 0;
  for (int step = 0; step < SS; ++step) {
    const int t = d ? (SS - 1 - step) : step;
    const float* act = par ? (hbuf + (size_t)buf * (HHd * 64))
                           : (a.xT + (size_t)t * (EE * 64));
    const float4* p = (const float4*)act + lane;
    float a0 = 0.f, a1 = 0.f, a2 = 0.f, a3 = 0.f;
    dot4(p, w0, w1, w2, w3, 64, a0, a1, a2, a3);
    part[w][0][lane] = a0; part[w][1][lane] = a1;
    part[w][2][lane] = a2; part[w][3][lane] = a3;
    __syncthreads();
    if (par == 0) {
      float gi = part[w][0][lane] + part[w + 1][0][lane] + bias[u];
      float gf = part[w][1][lane] + part[w + 1][1][lane] + bias[256 + u];
      float gg = part[w][2][lane] + part[w + 1][2][lane] + bias[512 + u];
      float go = part[w][3][lane] + part[w + 1][3][lane] + bias[768 + u];
      float c_old = cT[u * 64 + lane];
      float h_old = hbuf[(size_t)buf * (HHd * 64) + cidx(u, lane)];
      float i_ = sigm(gi), f_ = sigm(gf), o_ = sigm(go);
      float gn = tanhf(gg);
      float c2 = f_ * c_old + i_ * gn;
      float h2 = o_ * tanhf(c2);
      const bool m = (t < len);
      hbuf[(size_t)(buf ^ 1) * (HHd * 64) + cidx(u, lane)] = m ? h2 : h_old;
      cT[u * 64 + lane] = m ? c2 : c_old;
      a.bi[(size_t)t * (HD * 64) + cidx(d * 256 + u, lane)] = m ? h2 : 0.f;
    }
    buf ^= 1;
    gbar2<128>(flags, bid, ep); ep++;  // leading __syncthreads protects part[] reuse
  }
}

struct K4A {
  const float* bi; float* h0r; float* h1h;
  const float* wihs; const float* whhs; const float* bs;
  const float* h20; const float* c20;
  float* c0T; float* c1T;
  int* flags;   // 256 ints
};

// K4: 2-layer stack LSTM, software-pipelined: super-step t computes
// layer0(t) and layer1(t-1). 256 blocks x 512 thr. Blocks <128 = layer0.
__global__ __launch_bounds__(512) void k4(K4A a) {
  const int lane = threadIdx.x & 63;
  const int w = __builtin_amdgcn_readfirstlane(threadIdx.x >> 6);  // 0..7
  const int layer = (int)blockIdx.x >> 7;
  const int lb = (int)blockIdx.x & 127;
  const int unit = lb * 4 + (w >> 1);  // 0..511
  const int par = w & 1;               // 0 = x-part, 1 = h-part
  const size_t woff = (size_t)layer * (2048 * 512);
  const float* Wg = (par ? a.whhs : a.wihs) + woff;
  const float* w0 = Wg + (size_t)(0 * HD + unit) * HD;
  const float* w1 = Wg + (size_t)(1 * HD + unit) * HD;
  const float* w2 = Wg + (size_t)(2 * HD + unit) * HD;
  const float* w3 = Wg + (size_t)(3 * HD + unit) * HD;
  float* cT = layer ? a.c1T : a.c0T;
  __shared__ float part[8][4][64];
  if (par == 0) {
    if (layer == 0) a.h0r[cidx(unit, lane)] = a.h20[unit];            // ring slot 0
    else            a.h1h[cidx(unit, lane)] = a.h20[512 + unit];      // slot 0
    cT[unit * 64 + lane] = layer ? a.c20[512 + unit] : a.c20[unit];
  }
  int ep = 0;
  gbar2<256>(a.flags, blockIdx.x, ep); ep++;
  for (int t = 0; t <= SS; ++t) {
    const bool active = (layer == 0) ? (t < SS) : (t >= 1);
    float a0 = 0.f, a1 = 0.f, a2 = 0.f, a3 = 0.f;
    if (active) {
      const float* act;
      if (layer == 0)
        act = par ? (a.h0r + (size_t)(t & 1) * (HD * 64))    // h0(t-1)
                  : (a.bi + (size_t)t * (HD * 64));          // bi[t]
      else
        act = par ? (a.h1h + (size_t)(t - 1) * (HD * 64))    // h1(t-2)
                  : (a.h0r + (size_t)(t & 1) * (HD * 64));   // h0(t-1)
      const float4* p = (const float4*)act + lane;
      dot4(p, w0, w1, w2, w3, 128, a0, a1, a2, a3);
    }
    part[w][0][lane] = a0; part[w][1][lane] = a1;
    part[w][2][lane] = a2; part[w][3][lane] = a3;
    __syncthreads();
    if (active && par == 0) {
      const float* bs = a.bs + (size_t)layer * 2048;
      float gi = part[w][0][lane] + part[w + 1][0][lane] + bs[unit];
      float gf = part[w][1][lane] + part[w + 1][1][lane] + bs[512 + unit];
      float gg = part[w][2][lane] + part[w + 1][2][lane] + bs[1024 + unit];
      float go = part[w][3][lane] + part[w + 1][3][lane] + bs[1536 + unit];
      float c_old = cT[unit * 64 + lane];
      float i_ = sigm(gi), f_ = sigm(gf), o_ = sigm(go);
      float gn = tanhf(gg);
      float c2 = f_ * c_old + i_ * gn;
      float h2 = o_ * tanhf(c2);
      if (layer == 0) a.h0r[(size_t)((t + 1) & 1) * (HD * 64) + cidx(unit, lane)] = h2;
      else            a.h1h[(size_t)t * (HD * 64) + cidx(unit, lane)] = h2;  // h1(t-1)
      cT[unit * 64 + lane] = c2;
    }
    gbar2<256>(a.flags, blockIdx.x, ep); ep++;
  }
}

// K4b: feats[t][j][b] = h1(t) . W_tag[j] + b_tag[j]
__global__ __launch_bounds__(256) void k4b(const float* __restrict__ h1h,
                                           const float* __restrict__ Wtag,
                                           const float* __restrict__ btag,
                                           float* __restrict__ feats) {
  const int t = blockIdx.x;
  const int lane = threadIdx.x & 63;
  const int w = __builtin_amdgcn_readfirstlane(threadIdx.x >> 6);
  const int j0 = w * 6;
  const float4* p = (const float4*)(h1h + (size_t)(t + 1) * (HD * 64)) + lane;
  const float* r[6];
  float acc[6];
#pragma unroll
  for (int jj = 0; jj < 6; ++jj) {
    int j = j0 + jj; if (j > 21) j = 21;
    r[jj] = Wtag + (size_t)j * HD;
    acc[jj] = btag[j];
  }
#pragma unroll 2
  for (int c = 0; c < 128; ++c) {
    float4 h = p[c * 64];
    int k = c * 4;
#pragma unroll
    for (int jj = 0; jj < 6; ++jj) {
      acc[jj] = fmaf(h.x, r[jj][k], acc[jj]);
      acc[jj] = fmaf(h.y, r[jj][k + 1], acc[jj]);
      acc[jj] = fmaf(h.z, r[jj][k + 2], acc[jj]);
      acc[jj] = fmaf(h.w, r[jj][k + 3], acc[jj]);
    }
  }
#pragma unroll
  for (int jj = 0; jj < 6; ++jj) {
    int j = j0 + jj;
    if (j < NTAG) feats[((size_t)t * NTAG + j) * 64 + lane] = acc[jj];
  }
}

// K5: Viterbi decode, one block per batch element, backpointers in LDS.
__global__ __launch_bounds__(64) void k5(const float* __restrict__ feats,
                                         const float* __restrict__ trans,
                                         const int* __restrict__ lengths,
                                         float* __restrict__ out) {
  const int b = blockIdx.x;
  const int j = threadIdx.x;
  __shared__ float tr[NTAG * NTAG];
  __shared__ float sc[NTAG];
  __shared__ float term[NTAG];
  __shared__ unsigned char bp[SS - 1][NTAG];
  for (int i = j; i < NTAG * NTAG; i += 64) tr[i] = trans[i];
  const int len = lengths[b];
  float score = 0.f;
  __syncthreads();
  if (j < NTAG) {
    score = feats[(size_t)j * 64 + b] + tr[j * NTAG + TSTART];
    sc[j] = score;
  }
  __syncthreads();
  for (int t = 1; t < len; ++t) {
    float best = -3.4e38f; int bi_ = 0;
    if (j < NTAG) {
#pragma unroll
      for (int i = 0; i < NTAG; ++i) {
        float c = sc[i] + tr[j * NTAG + i];
        if (c > best) { best = c; bi_ = i; }   // strict > keeps first max (argmax semantics)
      }
      score = best + feats[((size_t)t * NTAG + j) * 64 + b];
      bp[t - 1][j] = (unsigned char)bi_;
    }
    __syncthreads();
    if (j < NTAG) sc[j] = score;
    __syncthreads();
  }
  if (j < NTAG) term[j] = score + tr[TSTOP * NTAG + j];
  __syncthreads();
  if (j == 0) {
    float bs = term[0]; int bt = 0;
    for (int i = 1; i < NTAG; ++i) if (term[i] > bs) { bs = term[i]; bt = i; }
    out[b] = bs;
    int tag = bt;
    for (int t = SS - 1; t >= 1; --t) {
      out[64 + (size_t)b * SS + t] = (float)tag;
      if (t < len) tag = bp[t - 1][tag];       // masked steps: identity backpointer
    }
    out[64 + (size_t)b * SS + 0] = (float)tag;
  }
}

extern "C" void kernel_launch(void* const* d_in, const int* in_sizes, int n_in,
                              void* d_out, int out_size, void* d_ws, size_t ws_size,
                              hipStream_t stream) {
  const int* sentence = (const int*)d_in[0];
  const int* lengths  = (const int*)d_in[1];
  const float* emb    = (const float*)d_in[2];
  const float* wih_f  = (const float*)d_in[3];
  const float* whh_f  = (const float*)d_in[4];
  const float* b_f    = (const float*)d_in[5];
  const float* wih_b  = (const float*)d_in[6];
  const float* whh_b  = (const float*)d_in[7];
  const float* b_b    = (const float*)d_in[8];
  const float* h10    = (const float*)d_in[9];
  const float* c10    = (const float*)d_in[10];
  const float* wihs   = (const float*)d_in[11];
  const float* whhs   = (const float*)d_in[12];
  const float* bs     = (const float*)d_in[13];
  const float* h20    = (const float*)d_in[14];
  const float* c20    = (const float*)d_in[15];
  const float* Wtag   = (const float*)d_in[16];
  const float* btag   = (const float*)d_in[17];
  const float* trans  = (const float*)d_in[18];
  float* ws = (float*)d_ws;
  float* out = (float*)d_out;
  int* barbase = (int*)(ws + OFF_BAR);

  // zero barrier flag arrays (ws is poisoned 0xAA before every call)
  hipMemsetAsync((void*)barbase, 0, 512 * sizeof(int) + 256 * sizeof(int), stream);

  k0<<<dim3(SS), dim3(256), 0, stream>>>(sentence, emb, ws + OFF_XT);

  K2A a2{ws + OFF_XT, ws + OFF_BI, wih_f, whh_f, b_f, wih_b, whh_b, b_b,
         h10, c10, lengths,
         ws + OFF_HF, ws + OFF_HB, ws + OFF_CF, ws + OFF_CB,
         barbase};
  k2<<<dim3(256), dim3(256), 0, stream>>>(a2);

  K4A a4{ws + OFF_BI, ws + OFF_H0R, ws + OFF_H1H, wihs, whhs, bs, h20, c20,
         ws + OFF_C0, ws + OFF_C1,
         barbase + 512};
  k4<<<dim3(256), dim3(512), 0, stream>>>(a4);

  k4b<<<dim3(SS), dim3(256), 0, stream>>>(ws + OFF_H1H, Wtag, btag, ws + OFF_FEATS);
  k5<<<dim3(BB), dim3(64), 0, stream>>>(ws + OFF_FEATS, trans, lengths, out);
}

// Round 3
// 26871.448 us; speedup vs baseline: 1.7538x; 1.5948x over previous
//
#include <hip/hip_runtime.h>
#include <cmath>

// ResLSTM+CRF on MI355X, fp32 vector-ALU implementation.
// R3: zero-fence design. Cross-block recurrent arrays (hbuf/h0r/h1h) are accessed
// ONLY via coherence-point ops (stores: relaxed agent atomics = sc0 sc1 write-through;
// loads: inline-asm global_load_dwordx4 sc0 sc1, batched + one vmcnt wait).
// Read-only data (weights/bias/bi/xT) uses ordinary cached loads and stays hot in
// L1/L2 across all steps (no invalidations). Waves partition the K dimension so each
// block reads each activation tile exactly once per step; LDS cross-wave reduction;
// c-state in registers.

namespace {
constexpr int SS = 512;     // seq len
constexpr int BB = 64;      // batch
constexpr int EE = 256;     // embed dim
constexpr int HHd = 256;    // half hidden (bi-lstm)
constexpr int HD = 512;     // hidden (stack)
constexpr int NTAG = 22;
constexpr int TSTART = 20;
constexpr int TSTOP = 21;

// ws offsets (in floats)
constexpr size_t OFF_BI    = 0;                                      // [512][512][64] chunked (ordinary)
constexpr size_t OFF_H1H   = OFF_BI    + (size_t)SS * HD * BB;       // [513][512][64] chunked (coherent)
constexpr size_t OFF_XT    = OFF_H1H   + (size_t)(SS + 1) * HD * BB; // [512][256][64] chunked (ordinary)
constexpr size_t OFF_FEATS = OFF_XT    + (size_t)SS * EE * BB;       // [512][22][64]
constexpr size_t OFF_H0R   = OFF_FEATS + (size_t)SS * NTAG * BB;     // [2][512][64] chunked (coherent)
constexpr size_t OFF_HF    = OFF_H0R   + 2 * (size_t)HD * BB;        // [2][256][64] chunked (coherent)
constexpr size_t OFF_HB    = OFF_HF    + 2 * (size_t)HHd * BB;
constexpr size_t OFF_BAR   = OFF_HB    + 2 * (size_t)HHd * BB;       // 768 ints of flags
}

__device__ __forceinline__ int cidx(int k, int lane) {
  return ((k >> 2) << 8) + (lane << 2) + (k & 3);
}

// Coherence-point 16B load: bypasses (possibly stale) L1/L2, reads L3/mem.
__device__ __forceinline__ float4 cload4(const float4* p) {
  float4 r;
  asm volatile("global_load_dwordx4 %0, %1, off sc0 sc1" : "=v"(r) : "v"(p));
  return r;
}
__device__ __forceinline__ void vwait0() {
  asm volatile("s_waitcnt vmcnt(0)" ::: "memory");
}
// Coherence-point 4B store (write-through, no dirty line in local L2).
__device__ __forceinline__ void cstore(float* p, float v) {
  __hip_atomic_store(p, v, __ATOMIC_RELAXED, __HIP_MEMORY_SCOPE_AGENT);
}

// Device barrier, no fences: per-block flag (relaxed agent store), 64-lane poll.
// Callers must vmcnt-drain their own coherent stores (vwait0) before entering.
template <int NBLK>
__device__ __forceinline__ void gbar(int* flags, int bid, int epoch) {
  __syncthreads();
  if (threadIdx.x == 0) {
    __hip_atomic_store(flags + bid, epoch + 1, __ATOMIC_RELAXED, __HIP_MEMORY_SCOPE_AGENT);
  }
  if (threadIdx.x < 64) {
    constexpr int PER = NBLK / 64;
    bool ok;
    do {
      ok = true;
#pragma unroll
      for (int i = 0; i < PER; ++i) {
        ok = ok && (__hip_atomic_load(flags + threadIdx.x * PER + i, __ATOMIC_RELAXED,
                                      __HIP_MEMORY_SCOPE_AGENT) > epoch);
      }
    } while (__any(!ok));
  }
  __syncthreads();
}

__device__ __forceinline__ float sigm(float x) { return 1.f / (1.f + expf(-x)); }
__device__ __forceinline__ float comp4(float4 v, int w) {
  return (w == 0) ? v.x : (w == 1) ? v.y : (w == 2) ? v.z : v.w;
}

// K0: gather embeddings, transpose to chunked [t][e-chunk][lane][4]
__global__ __launch_bounds__(256) void k0(const int* __restrict__ sent,
                                          const float* __restrict__ emb,
                                          float* __restrict__ xT) {
  const int t = blockIdx.x;
  const int lane = threadIdx.x & 63;
  const int w = __builtin_amdgcn_readfirstlane(threadIdx.x >> 6); // 0..3
  __shared__ float tile[64][65];
  __shared__ int rows[64];
  if (threadIdx.x < 64) rows[threadIdx.x] = sent[(size_t)threadIdx.x * SS + t];
  __syncthreads();
  float4* xT4 = (float4*)xT;
  for (int e0 = 0; e0 < EE; e0 += 64) {
    for (int bb = 0; bb < 16; ++bb) {
      int b = bb * 4 + w;
      tile[b][lane] = emb[(size_t)rows[b] * EE + e0 + lane];
    }
    __syncthreads();
    for (int r = 0; r < 4; ++r) {
      int ecl = w * 4 + r;
      int ec = (e0 >> 2) + ecl;
      float4 v = make_float4(tile[lane][ecl * 4 + 0], tile[lane][ecl * 4 + 1],
                             tile[lane][ecl * 4 + 2], tile[lane][ecl * 4 + 3]);
      xT4[((size_t)t * 64 + ec) * 64 + lane] = v;
    }
    __syncthreads();
  }
}

struct K2A {
  const float* xT; float* bi;
  const float* wih_f; const float* whh_f; const float* b_f;
  const float* wih_b; const float* whh_b; const float* b_b;
  const float* h10; const float* c10; const int* lengths;
  float* hf; float* hb;
  int* flags;   // [0..127] fwd, [128..255] bwd
};

// K2: BiLSTM. 256 blocks x 256 thr. Block (d = bid>>7, lb = bid&127) owns units
// {2lb, 2lb+1} of direction d. Waves partition K: w<2 -> x slices (ordinary, xT),
// w>=2 -> h slices (coherent, hbuf ring). 8 gate-row accs each; LDS reduction.
__global__ __launch_bounds__(256) void k2(K2A a) {
  const int lane = threadIdx.x & 63;
  const int w = __builtin_amdgcn_readfirstlane(threadIdx.x >> 6); // 0..3
  const int d = (int)blockIdx.x >> 7;
  const int lb = (int)blockIdx.x & 127;
  int* flags = a.flags + d * 128;
  const int u0 = lb * 2;
  const bool hpart = (w >= 2);
  const int sl = w & 1;            // 128-k slice within part
  const float* Wmat = hpart ? (d ? a.whh_b : a.whh_f) : (d ? a.wih_b : a.wih_f);
  const float* bias = d ? a.b_b : a.b_f;
  const float* wr[8];
#pragma unroll
  for (int g = 0; g < 4; ++g)
#pragma unroll
    for (int ul = 0; ul < 2; ++ul)
      wr[g * 2 + ul] = Wmat + (size_t)(g * HHd + u0 + ul) * 256 + sl * 128;
  float* hbuf = d ? a.hb : a.hf;
  const int len = a.lengths[lane];
  __shared__ float4 part[4][2][64];
  float c_st = 0.f, h_old = 0.f;
  if (w < 2) {
    int u = u0 + w;
    h_old = a.h10[d * 256 + u];
    c_st = a.c10[d * 256 + u];
    cstore(&hbuf[cidx(u, lane)], h_old);
    vwait0();
  }
  int ep = 0;
  gbar<128>(flags, lb, ep); ep++;
  int buf = 0;
  for (int step = 0; step < SS; ++step) {
    const int t = d ? (SS - 1 - step) : step;
    const float* actbase = hpart ? (hbuf + (size_t)buf * (HHd * 64))
                                 : (a.xT + (size_t)t * (EE * 64));
    const float4* p = (const float4*)actbase + (size_t)(sl * 32) * 64 + lane;
    float acc[8] = {0, 0, 0, 0, 0, 0, 0, 0};
    for (int grp = 0; grp < 2; ++grp) {
      float4 va[16];
      const float4* pg = p + (size_t)grp * 16 * 64;
      if (hpart) {
#pragma unroll
        for (int c = 0; c < 16; ++c) va[c] = cload4(pg + (size_t)c * 64);
        vwait0();
      } else {
#pragma unroll
        for (int c = 0; c < 16; ++c) va[c] = pg[(size_t)c * 64];
      }
#pragma unroll
      for (int c = 0; c < 16; ++c) {
        const int k = grp * 64 + c * 4;
        float hv[4] = {va[c].x, va[c].y, va[c].z, va[c].w};
#pragma unroll
        for (int j = 0; j < 4; ++j)
#pragma unroll
          for (int r = 0; r < 8; ++r)
            acc[r] = fmaf(hv[j], wr[r][k + j], acc[r]);
      }
    }
    part[w][0][lane] = make_float4(acc[0], acc[1], acc[2], acc[3]);
    part[w][1][lane] = make_float4(acc[4], acc[5], acc[6], acc[7]);
    __syncthreads();
    if (w < 2) {
      float4 q0 = make_float4(0, 0, 0, 0), q1 = make_float4(0, 0, 0, 0);
#pragma unroll
      for (int wv = 0; wv < 4; ++wv) {
        float4 t0 = part[wv][0][lane], t1 = part[wv][1][lane];
        q0.x += t0.x; q0.y += t0.y; q0.z += t0.z; q0.w += t0.w;
        q1.x += t1.x; q1.y += t1.y; q1.z += t1.z; q1.w += t1.w;
      }
      const int u = u0 + w;
      // rows r=g*2+ul: q0 = {i.u0, i.u1, f.u0, f.u1}, q1 = {g.u0, g.u1, o.u0, o.u1}
      float gi = (w ? q0.y : q0.x) + bias[u];
      float gf = (w ? q0.w : q0.z) + bias[256 + u];
      float gg = (w ? q1.y : q1.x) + bias[512 + u];
      float go = (w ? q1.w : q1.z) + bias[768 + u];
      float i_ = sigm(gi), f_ = sigm(gf), o_ = sigm(go);
      float gn = tanhf(gg);
      float c2 = f_ * c_st + i_ * gn;
      float h2 = o_ * tanhf(c2);
      const bool m = (t < len);
      h2 = m ? h2 : h_old;
      c_st = m ? c2 : c_st;
      h_old = h2;
      cstore(&hbuf[(size_t)(buf ^ 1) * (HHd * 64) + cidx(u, lane)], h2);
      a.bi[(size_t)t * (HD * 64) + cidx(d * 256 + u, lane)] = m ? h2 : 0.f; // ordinary
      vwait0();   // drain coherent store before signaling
    }
    buf ^= 1;
    gbar<128>(flags, lb, ep); ep++;
  }
}

struct K4A {
  const float* bi; float* h0r; float* h1h;
  const float* wihs; const float* whhs; const float* bs;
  const float* h20; const float* c20;
  int* flags;   // 256 ints
};

// K4: 2-layer stack LSTM, software-pipelined (super-step t: layer0 t, layer1 t-1).
// 256 blocks x 512 thr. Block (layer = bid>>7, lb = bid&127) owns units 4lb..4lb+3.
// Waves partition z=[x(512); h(512)]: w<4 -> x slice 128w.. (bi ordinary for layer0,
// h0r coherent for layer1), w>=4 -> h slice (h0r / h1h, coherent). 16 accs; LDS reduce.
__global__ __launch_bounds__(512) void k4(K4A a) {
  const int lane = threadIdx.x & 63;
  const int w = __builtin_amdgcn_readfirstlane(threadIdx.x >> 6);  // 0..7
  const int layer = (int)blockIdx.x >> 7;
  const int lb = (int)blockIdx.x & 127;
  const int u0 = lb * 4;
  const bool hpart = (w >= 4);
  const int sl = w & 3;            // 128-k slice within part
  const float* Wmat = (hpart ? a.whhs : a.wihs) + (size_t)layer * (2048 * 512);
  const float* wr[16];
#pragma unroll
  for (int g = 0; g < 4; ++g)
#pragma unroll
    for (int ul = 0; ul < 4; ++ul)
      wr[g * 4 + ul] = Wmat + (size_t)(g * HD + u0 + ul) * HD + sl * 128;
  __shared__ float4 part[8][4][64];
  float c_st = 0.f;
  if (w < 4) {
    const int u = u0 + w;
    c_st = a.c20[layer * 512 + u];
    float h0i = a.h20[layer * 512 + u];
    if (layer == 0) cstore(&a.h0r[cidx(u, lane)], h0i);
    else            cstore(&a.h1h[cidx(u, lane)], h0i);
    vwait0();
  }
  int ep = 0;
  gbar<256>(a.flags, blockIdx.x, ep); ep++;
  for (int t = 0; t <= SS; ++t) {
    const bool active = (layer == 0) ? (t < SS) : (t >= 1);
    float acc[16] = {0, 0, 0, 0, 0, 0, 0, 0, 0, 0, 0, 0, 0, 0, 0, 0};
    if (active) {
      const float* actbase;
      bool coh;
      if (layer == 0) {
        actbase = hpart ? (a.h0r + (size_t)(t & 1) * (HD * 64))
                        : (a.bi + (size_t)t * (HD * 64));
        coh = hpart;
      } else {
        actbase = hpart ? (a.h1h + (size_t)(t - 1) * (HD * 64))
                        : (a.h0r + (size_t)(t & 1) * (HD * 64));
        coh = true;
      }
      const float4* p = (const float4*)actbase + (size_t)(sl * 32) * 64 + lane;
      for (int grp = 0; grp < 2; ++grp) {
        float4 va[16];
        const float4* pg = p + (size_t)grp * 16 * 64;
        if (coh) {
#pragma unroll
          for (int c = 0; c < 16; ++c) va[c] = cload4(pg + (size_t)c * 64);
          vwait0();
        } else {
#pragma unroll
          for (int c = 0; c < 16; ++c) va[c] = pg[(size_t)c * 64];
        }
#pragma unroll
        for (int c = 0; c < 16; ++c) {
          const int k = grp * 64 + c * 4;
          float hv[4] = {va[c].x, va[c].y, va[c].z, va[c].w};
#pragma unroll
          for (int j = 0; j < 4; ++j)
#pragma unroll
            for (int r = 0; r < 16; ++r)
              acc[r] = fmaf(hv[j], wr[r][k + j], acc[r]);
        }
      }
    }
    part[w][0][lane] = make_float4(acc[0], acc[1], acc[2], acc[3]);
    part[w][1][lane] = make_float4(acc[4], acc[5], acc[6], acc[7]);
    part[w][2][lane] = make_float4(acc[8], acc[9], acc[10], acc[11]);
    part[w][3][lane] = make_float4(acc[12], acc[13], acc[14], acc[15]);
    __syncthreads();
    if (active && w < 4) {
      float4 q[4];
#pragma unroll
      for (int g = 0; g < 4; ++g) q[g] = make_float4(0, 0, 0, 0);
#pragma unroll
      for (int wv = 0; wv < 8; ++wv)
#pragma unroll
        for (int g = 0; g < 4; ++g) {
          float4 tv = part[wv][g][lane];
          q[g].x += tv.x; q[g].y += tv.y; q[g].z += tv.z; q[g].w += tv.w;
        }
      const int u = u0 + w;
      const float* bsl = a.bs + (size_t)layer * 2048;
      float gi = comp4(q[0], w) + bsl[u];
      float gf = comp4(q[1], w) + bsl[512 + u];
      float gg = comp4(q[2], w) + bsl[1024 + u];
      float go = comp4(q[3], w) + bsl[1536 + u];
      float i_ = sigm(gi), f_ = sigm(gf), o_ = sigm(go);
      float gn = tanhf(gg);
      float c2 = f_ * c_st + i_ * gn;
      float h2 = o_ * tanhf(c2);
      c_st = c2;
      if (layer == 0)
        cstore(&a.h0r[(size_t)((t + 1) & 1) * (HD * 64) + cidx(u, lane)], h2);
      else
        cstore(&a.h1h[(size_t)t * (HD * 64) + cidx(u, lane)], h2);
      vwait0();
    }
    gbar<256>(a.flags, blockIdx.x, ep); ep++;
  }
}

// K4b: feats[t][j][b] = h1(t) . W_tag[j] + b_tag[j]
__global__ __launch_bounds__(256) void k4b(const float* __restrict__ h1h,
                                           const float* __restrict__ Wtag,
                                           const float* __restrict__ btag,
                                           float* __restrict__ feats) {
  const int t = blockIdx.x;
  const int lane = threadIdx.x & 63;
  const int w = __builtin_amdgcn_readfirstlane(threadIdx.x >> 6);
  const int j0 = w * 6;
  const float4* p = (const float4*)(h1h + (size_t)(t + 1) * (HD * 64)) + lane;
  const float* r[6];
  float acc[6];
#pragma unroll
  for (int jj = 0; jj < 6; ++jj) {
    int j = j0 + jj; if (j > 21) j = 21;
    r[jj] = Wtag + (size_t)j * HD;
    acc[jj] = btag[j];
  }
#pragma unroll 2
  for (int c = 0; c < 128; ++c) {
    float4 h = p[(size_t)c * 64];
    int k = c * 4;
#pragma unroll
    for (int jj = 0; jj < 6; ++jj) {
      acc[jj] = fmaf(h.x, r[jj][k], acc[jj]);
      acc[jj] = fmaf(h.y, r[jj][k + 1], acc[jj]);
      acc[jj] = fmaf(h.z, r[jj][k + 2], acc[jj]);
      acc[jj] = fmaf(h.w, r[jj][k + 3], acc[jj]);
    }
  }
#pragma unroll
  for (int jj = 0; jj < 6; ++jj) {
    int j = j0 + jj;
    if (j < NTAG) feats[((size_t)t * NTAG + j) * 64 + lane] = acc[jj];
  }
}

// K5: Viterbi decode, one block per batch element, backpointers in LDS.
__global__ __launch_bounds__(64) void k5(const float* __restrict__ feats,
                                         const float* __restrict__ trans,
                                         const int* __restrict__ lengths,
                                         float* __restrict__ out) {
  const int b = blockIdx.x;
  const int j = threadIdx.x;
  __shared__ float tr[NTAG * NTAG];
  __shared__ float sc[NTAG];
  __shared__ float term[NTAG];
  __shared__ unsigned char bp[SS - 1][NTAG];
  for (int i = j; i < NTAG * NTAG; i += 64) tr[i] = trans[i];
  const int len = lengths[b];
  float score = 0.f;
  __syncthreads();
  if (j < NTAG) {
    score = feats[(size_t)j * 64 + b] + tr[j * NTAG + TSTART];
    sc[j] = score;
  }
  __syncthreads();
  for (int t = 1; t < len; ++t) {
    float best = -3.4e38f; int bi_ = 0;
    if (j < NTAG) {
#pragma unroll
      for (int i = 0; i < NTAG; ++i) {
        float c = sc[i] + tr[j * NTAG + i];
        if (c > best) { best = c; bi_ = i; }   // strict > keeps first max
      }
      score = best + feats[((size_t)t * NTAG + j) * 64 + b];
      bp[t - 1][j] = (unsigned char)bi_;
    }
    __syncthreads();
    if (j < NTAG) sc[j] = score;
    __syncthreads();
  }
  if (j < NTAG) term[j] = score + tr[TSTOP * NTAG + j];
  __syncthreads();
  if (j == 0) {
    float bs = term[0]; int bt = 0;
    for (int i = 1; i < NTAG; ++i) if (term[i] > bs) { bs = term[i]; bt = i; }
    out[b] = bs;
    int tag = bt;
    for (int t = SS - 1; t >= 1; --t) {
      out[64 + (size_t)b * SS + t] = (float)tag;
      if (t < len) tag = bp[t - 1][tag];
    }
    out[64 + (size_t)b * SS + 0] = (float)tag;
  }
}

extern "C" void kernel_launch(void* const* d_in, const int* in_sizes, int n_in,
                              void* d_out, int out_size, void* d_ws, size_t ws_size,
                              hipStream_t stream) {
  const int* sentence = (const int*)d_in[0];
  const int* lengths  = (const int*)d_in[1];
  const float* emb    = (const float*)d_in[2];
  const float* wih_f  = (const float*)d_in[3];
  const float* whh_f  = (const float*)d_in[4];
  const float* b_f    = (const float*)d_in[5];
  const float* wih_b  = (const float*)d_in[6];
  const float* whh_b  = (const float*)d_in[7];
  const float* b_b    = (const float*)d_in[8];
  const float* h10    = (const float*)d_in[9];
  const float* c10    = (const float*)d_in[10];
  const float* wihs   = (const float*)d_in[11];
  const float* whhs   = (const float*)d_in[12];
  const float* bs     = (const float*)d_in[13];
  const float* h20    = (const float*)d_in[14];
  const float* c20    = (const float*)d_in[15];
  const float* Wtag   = (const float*)d_in[16];
  const float* btag   = (const float*)d_in[17];
  const float* trans  = (const float*)d_in[18];
  float* ws = (float*)d_ws;
  float* out = (float*)d_out;
  int* barbase = (int*)(ws + OFF_BAR);

  // zero barrier flag arrays (ws is poisoned 0xAA before every call)
  hipMemsetAsync((void*)barbase, 0, 768 * sizeof(int), stream);

  k0<<<dim3(SS), dim3(256), 0, stream>>>(sentence, emb, ws + OFF_XT);

  K2A a2{ws + OFF_XT, ws + OFF_BI, wih_f, whh_f, b_f, wih_b, whh_b, b_b,
         h10, c10, lengths,
         ws + OFF_HF, ws + OFF_HB,
         barbase};
  k2<<<dim3(256), dim3(256), 0, stream>>>(a2);

  K4A a4{ws + OFF_BI, ws + OFF_H0R, ws + OFF_H1H, wihs, whhs, bs, h20, c20,
         barbase + 512};
  k4<<<dim3(256), dim3(512), 0, stream>>>(a4);

  k4b<<<dim3(SS), dim3(256), 0, stream>>>(ws + OFF_H1H, Wtag, btag, ws + OFF_FEATS);
  k5<<<dim3(BB), dim3(64), 0, stream>>>(ws + OFF_FEATS, trans, lengths, out);
}

// Round 4
// 24875.191 us; speedup vs baseline: 1.8946x; 1.0803x over previous
//
#include <hip/hip_runtime.h>
#include <cmath>

// ResLSTM+CRF on MI355X, fp32 vector-ALU implementation.
// R4: centralized-release device barrier. Arrival = per-block flag store (no RMW);
// ONLY block 0 polls the flag array (one wave); it publishes a single release word;
// all other blocks poll that one word with one lane + s_sleep backoff. This removes
// the R3 poll-storm (256 blocks x 64 lanes hammering 16 cachelines continuously).
// Cross-block recurrent arrays (hbuf/h0r/h1h) accessed only via coherence-point ops
// (stores: relaxed agent atomics; loads: global_load_dwordx4 sc0 sc1 batched + vmcnt).
// Read-only data (weights/bias/bi/xT) uses ordinary cached loads, hot in L1/L2.

namespace {
constexpr int SS = 512;     // seq len
constexpr int BB = 64;      // batch
constexpr int EE = 256;     // embed dim
constexpr int HHd = 256;    // half hidden (bi-lstm)
constexpr int HD = 512;     // hidden (stack)
constexpr int NTAG = 22;
constexpr int TSTART = 20;
constexpr int TSTOP = 21;

// ws offsets (in floats)
constexpr size_t OFF_BI    = 0;                                      // [512][512][64] chunked (ordinary)
constexpr size_t OFF_H1H   = OFF_BI    + (size_t)SS * HD * BB;       // [513][512][64] chunked (coherent)
constexpr size_t OFF_XT    = OFF_H1H   + (size_t)(SS + 1) * HD * BB; // [512][256][64] chunked (ordinary)
constexpr size_t OFF_FEATS = OFF_XT    + (size_t)SS * EE * BB;       // [512][22][64]
constexpr size_t OFF_H0R   = OFF_FEATS + (size_t)SS * NTAG * BB;     // [2][512][64] chunked (coherent)
constexpr size_t OFF_HF    = OFF_H0R   + 2 * (size_t)HD * BB;        // [2][256][64] chunked (coherent)
constexpr size_t OFF_HB    = OFF_HF    + 2 * (size_t)HHd * BB;
constexpr size_t OFF_BAR   = OFF_HB    + 2 * (size_t)HHd * BB;       // barrier state (ints)
// barrier regions (ints from OFF_BAR):
//   k2 fwd: flags @0   (128), release @160
//   k2 bwd: flags @384 (128), release @544
//   k4:     flags @768 (256), release @1056
constexpr int BAR_INTS = 1152;
}

__device__ __forceinline__ int cidx(int k, int lane) {
  return ((k >> 2) << 8) + (lane << 2) + (k & 3);
}

// Coherence-point 16B load: bypasses (possibly stale) L1/L2, reads L3/mem.
__device__ __forceinline__ float4 cload4(const float4* p) {
  float4 r;
  asm volatile("global_load_dwordx4 %0, %1, off sc0 sc1" : "=v"(r) : "v"(p));
  return r;
}
__device__ __forceinline__ void vwait0() {
  asm volatile("s_waitcnt vmcnt(0)" ::: "memory");
}
// Coherence-point 4B store (write-through, no dirty line in local L2).
__device__ __forceinline__ void cstore(float* p, float v) {
  __hip_atomic_store(p, v, __ATOMIC_RELAXED, __HIP_MEMORY_SCOPE_AGENT);
}

// Centralized-release device barrier, no fences.
// Callers must vmcnt-drain their own coherent stores (vwait0) before entering.
template <int NBLK>
__device__ __forceinline__ void gbarC(int* flags, int* release, int bid, int epoch) {
  __syncthreads();
  if (threadIdx.x == 0) {
    __hip_atomic_store(flags + bid, epoch + 1, __ATOMIC_RELAXED, __HIP_MEMORY_SCOPE_AGENT);
  }
  if (bid == 0) {
    if (threadIdx.x < 64) {
      constexpr int PER = NBLK / 64;
      bool ok;
      do {
        ok = true;
#pragma unroll
        for (int i = 0; i < PER; ++i) {
          ok = ok && (__hip_atomic_load(flags + threadIdx.x * PER + i, __ATOMIC_RELAXED,
                                        __HIP_MEMORY_SCOPE_AGENT) > epoch);
        }
      } while (__any(!ok));
      if (threadIdx.x == 0) {
        __hip_atomic_store(release, epoch + 1, __ATOMIC_RELAXED, __HIP_MEMORY_SCOPE_AGENT);
      }
    }
  } else {
    if (threadIdx.x == 0) {
      while (__hip_atomic_load(release, __ATOMIC_RELAXED, __HIP_MEMORY_SCOPE_AGENT) <= epoch) {
        __builtin_amdgcn_s_sleep(1);
      }
    }
  }
  __syncthreads();
}

__device__ __forceinline__ float sigm(float x) { return 1.f / (1.f + expf(-x)); }
__device__ __forceinline__ float comp4(float4 v, int w) {
  return (w == 0) ? v.x : (w == 1) ? v.y : (w == 2) ? v.z : v.w;
}

// K0: gather embeddings, transpose to chunked [t][e-chunk][lane][4]
__global__ __launch_bounds__(256) void k0(const int* __restrict__ sent,
                                          const float* __restrict__ emb,
                                          float* __restrict__ xT) {
  const int t = blockIdx.x;
  const int lane = threadIdx.x & 63;
  const int w = __builtin_amdgcn_readfirstlane(threadIdx.x >> 6); // 0..3
  __shared__ float tile[64][65];
  __shared__ int rows[64];
  if (threadIdx.x < 64) rows[threadIdx.x] = sent[(size_t)threadIdx.x * SS + t];
  __syncthreads();
  float4* xT4 = (float4*)xT;
  for (int e0 = 0; e0 < EE; e0 += 64) {
    for (int bb = 0; bb < 16; ++bb) {
      int b = bb * 4 + w;
      tile[b][lane] = emb[(size_t)rows[b] * EE + e0 + lane];
    }
    __syncthreads();
    for (int r = 0; r < 4; ++r) {
      int ecl = w * 4 + r;
      int ec = (e0 >> 2) + ecl;
      float4 v = make_float4(tile[lane][ecl * 4 + 0], tile[lane][ecl * 4 + 1],
                             tile[lane][ecl * 4 + 2], tile[lane][ecl * 4 + 3]);
      xT4[((size_t)t * 64 + ec) * 64 + lane] = v;
    }
    __syncthreads();
  }
}

struct K2A {
  const float* xT; float* bi;
  const float* wih_f; const float* whh_f; const float* b_f;
  const float* wih_b; const float* whh_b; const float* b_b;
  const float* h10; const float* c10; const int* lengths;
  float* hf; float* hb;
  int* bar;   // barrier base (ints)
};

// K2: BiLSTM. 256 blocks x 256 thr. Block (d = bid>>7, lb = bid&127) owns units
// {2lb, 2lb+1} of direction d. Waves partition K: w<2 -> x slices (ordinary, xT),
// w>=2 -> h slices (coherent, hbuf ring). 8 gate-row accs each; LDS reduction.
__global__ __launch_bounds__(256) void k2(K2A a) {
  const int lane = threadIdx.x & 63;
  const int w = __builtin_amdgcn_readfirstlane(threadIdx.x >> 6); // 0..3
  const int d = (int)blockIdx.x >> 7;
  const int lb = (int)blockIdx.x & 127;
  int* flags = a.bar + d * 384;
  int* release = a.bar + d * 384 + 160;
  const int u0 = lb * 2;
  const bool hpart = (w >= 2);
  const int sl = w & 1;            // 128-k slice within part
  const float* Wmat = hpart ? (d ? a.whh_b : a.whh_f) : (d ? a.wih_b : a.wih_f);
  const float* bias = d ? a.b_b : a.b_f;
  const float* wr[8];
#pragma unroll
  for (int g = 0; g < 4; ++g)
#pragma unroll
    for (int ul = 0; ul < 2; ++ul)
      wr[g * 2 + ul] = Wmat + (size_t)(g * HHd + u0 + ul) * 256 + sl * 128;
  float* hbuf = d ? a.hb : a.hf;
  const int len = a.lengths[lane];
  __shared__ float4 part[4][2][64];
  float c_st = 0.f, h_old = 0.f;
  if (w < 2) {
    int u = u0 + w;
    h_old = a.h10[d * 256 + u];
    c_st = a.c10[d * 256 + u];
    cstore(&hbuf[cidx(u, lane)], h_old);
    vwait0();
  }
  int ep = 0;
  gbarC<128>(flags, release, lb, ep); ep++;
  int buf = 0;
  for (int step = 0; step < SS; ++step) {
    const int t = d ? (SS - 1 - step) : step;
    const float* actbase = hpart ? (hbuf + (size_t)buf * (HHd * 64))
                                 : (a.xT + (size_t)t * (EE * 64));
    const float4* p = (const float4*)actbase + (size_t)(sl * 32) * 64 + lane;
    float acc[8] = {0, 0, 0, 0, 0, 0, 0, 0};
    for (int grp = 0; grp < 2; ++grp) {
      float4 va[16];
      const float4* pg = p + (size_t)grp * 16 * 64;
      if (hpart) {
#pragma unroll
        for (int c = 0; c < 16; ++c) va[c] = cload4(pg + (size_t)c * 64);
        vwait0();
      } else {
#pragma unroll
        for (int c = 0; c < 16; ++c) va[c] = pg[(size_t)c * 64];
      }
#pragma unroll
      for (int c = 0; c < 16; ++c) {
        const int k = grp * 64 + c * 4;
        float hv[4] = {va[c].x, va[c].y, va[c].z, va[c].w};
#pragma unroll
        for (int j = 0; j < 4; ++j)
#pragma unroll
          for (int r = 0; r < 8; ++r)
            acc[r] = fmaf(hv[j], wr[r][k + j], acc[r]);
      }
    }
    part[w][0][lane] = make_float4(acc[0], acc[1], acc[2], acc[3]);
    part[w][1][lane] = make_float4(acc[4], acc[5], acc[6], acc[7]);
    __syncthreads();
    if (w < 2) {
      float4 q0 = make_float4(0, 0, 0, 0), q1 = make_float4(0, 0, 0, 0);
#pragma unroll
      for (int wv = 0; wv < 4; ++wv) {
        float4 t0 = part[wv][0][lane], t1 = part[wv][1][lane];
        q0.x += t0.x; q0.y += t0.y; q0.z += t0.z; q0.w += t0.w;
        q1.x += t1.x; q1.y += t1.y; q1.z += t1.z; q1.w += t1.w;
      }
      const int u = u0 + w;
      float gi = (w ? q0.y : q0.x) + bias[u];
      float gf = (w ? q0.w : q0.z) + bias[256 + u];
      float gg = (w ? q1.y : q1.x) + bias[512 + u];
      float go = (w ? q1.w : q1.z) + bias[768 + u];
      float i_ = sigm(gi), f_ = sigm(gf), o_ = sigm(go);
      float gn = tanhf(gg);
      float c2 = f_ * c_st + i_ * gn;
      float h2 = o_ * tanhf(c2);
      const bool m = (t < len);
      h2 = m ? h2 : h_old;
      c_st = m ? c2 : c_st;
      h_old = h2;
      cstore(&hbuf[(size_t)(buf ^ 1) * (HHd * 64) + cidx(u, lane)], h2);
      a.bi[(size_t)t * (HD * 64) + cidx(d * 256 + u, lane)] = m ? h2 : 0.f; // ordinary
      vwait0();   // drain coherent store before signaling
    }
    buf ^= 1;
    gbarC<128>(flags, release, lb, ep); ep++;
  }
}

struct K4A {
  const float* bi; float* h0r; float* h1h;
  const float* wihs; const float* whhs; const float* bs;
  const float* h20; const float* c20;
  int* bar;   // barrier base (ints)
};

// K4: 2-layer stack LSTM, software-pipelined (super-step t: layer0 t, layer1 t-1).
// 256 blocks x 512 thr. Block (layer = bid>>7, lb = bid&127) owns units 4lb..4lb+3.
// Waves partition z=[x(512); h(512)]: w<4 -> x slice (bi ordinary for layer0,
// h0r coherent for layer1), w>=4 -> h slice (h0r / h1h, coherent). 16 accs; LDS reduce.
__global__ __launch_bounds__(512) void k4(K4A a) {
  const int lane = threadIdx.x & 63;
  const int w = __builtin_amdgcn_readfirstlane(threadIdx.x >> 6);  // 0..7
  const int layer = (int)blockIdx.x >> 7;
  const int lb = (int)blockIdx.x & 127;
  const int u0 = lb * 4;
  const bool hpart = (w >= 4);
  const int sl = w & 3;            // 128-k slice within part
  const float* Wmat = (hpart ? a.whhs : a.wihs) + (size_t)layer * (2048 * 512);
  const float* wr[16];
#pragma unroll
  for (int g = 0; g < 4; ++g)
#pragma unroll
    for (int ul = 0; ul < 4; ++ul)
      wr[g * 4 + ul] = Wmat + (size_t)(g * HD + u0 + ul) * HD + sl * 128;
  __shared__ float4 part[8][4][64];
  float c_st = 0.f;
  if (w < 4) {
    const int u = u0 + w;
    c_st = a.c20[layer * 512 + u];
    float h0i = a.h20[layer * 512 + u];
    if (layer == 0) cstore(&a.h0r[cidx(u, lane)], h0i);
    else            cstore(&a.h1h[cidx(u, lane)], h0i);
    vwait0();
  }
  int ep = 0;
  gbarC<256>(a.bar, a.bar + 288, blockIdx.x, ep); ep++;
  for (int t = 0; t <= SS; ++t) {
    const bool active = (layer == 0) ? (t < SS) : (t >= 1);
    float acc[16] = {0, 0, 0, 0, 0, 0, 0, 0, 0, 0, 0, 0, 0, 0, 0, 0};
    if (active) {
      const float* actbase;
      bool coh;
      if (layer == 0) {
        actbase = hpart ? (a.h0r + (size_t)(t & 1) * (HD * 64))
                        : (a.bi + (size_t)t * (HD * 64));
        coh = hpart;
      } else {
        actbase = hpart ? (a.h1h + (size_t)(t - 1) * (HD * 64))
                        : (a.h0r + (size_t)(t & 1) * (HD * 64));
        coh = true;
      }
      const float4* p = (const float4*)actbase + (size_t)(sl * 32) * 64 + lane;
      for (int grp = 0; grp < 2; ++grp) {
        float4 va[16];
        const float4* pg = p + (size_t)grp * 16 * 64;
        if (coh) {
#pragma unroll
          for (int c = 0; c < 16; ++c) va[c] = cload4(pg + (size_t)c * 64);
          vwait0();
        } else {
#pragma unroll
          for (int c = 0; c < 16; ++c) va[c] = pg[(size_t)c * 64];
        }
#pragma unroll
        for (int c = 0; c < 16; ++c) {
          const int k = grp * 64 + c * 4;
          float hv[4] = {va[c].x, va[c].y, va[c].z, va[c].w};
#pragma unroll
          for (int j = 0; j < 4; ++j)
#pragma unroll
            for (int r = 0; r < 16; ++r)
              acc[r] = fmaf(hv[j], wr[r][k + j], acc[r]);
        }
      }
    }
    part[w][0][lane] = make_float4(acc[0], acc[1], acc[2], acc[3]);
    part[w][1][lane] = make_float4(acc[4], acc[5], acc[6], acc[7]);
    part[w][2][lane] = make_float4(acc[8], acc[9], acc[10], acc[11]);
    part[w][3][lane] = make_float4(acc[12], acc[13], acc[14], acc[15]);
    __syncthreads();
    if (active && w < 4) {
      float4 q[4];
#pragma unroll
      for (int g = 0; g < 4; ++g) q[g] = make_float4(0, 0, 0, 0);
#pragma unroll
      for (int wv = 0; wv < 8; ++wv)
#pragma unroll
        for (int g = 0; g < 4; ++g) {
          float4 tv = part[wv][g][lane];
          q[g].x += tv.x; q[g].y += tv.y; q[g].z += tv.z; q[g].w += tv.w;
        }
      const int u = u0 + w;
      const float* bsl = a.bs + (size_t)layer * 2048;
      float gi = comp4(q[0], w) + bsl[u];
      float gf = comp4(q[1], w) + bsl[512 + u];
      float gg = comp4(q[2], w) + bsl[1024 + u];
      float go = comp4(q[3], w) + bsl[1536 + u];
      float i_ = sigm(gi), f_ = sigm(gf), o_ = sigm(go);
      float gn = tanhf(gg);
      float c2 = f_ * c_st + i_ * gn;
      float h2 = o_ * tanhf(c2);
      c_st = c2;
      if (layer == 0)
        cstore(&a.h0r[(size_t)((t + 1) & 1) * (HD * 64) + cidx(u, lane)], h2);
      else
        cstore(&a.h1h[(size_t)t * (HD * 64) + cidx(u, lane)], h2);
      vwait0();
    }
    gbarC<256>(a.bar, a.bar + 288, blockIdx.x, ep); ep++;
  }
}

// K4b: feats[t][j][b] = h1(t) . W_tag[j] + b_tag[j]
__global__ __launch_bounds__(256) void k4b(const float* __restrict__ h1h,
                                           const float* __restrict__ Wtag,
                                           const float* __restrict__ btag,
                                           float* __restrict__ feats) {
  const int t = blockIdx.x;
  const int lane = threadIdx.x & 63;
  const int w = __builtin_amdgcn_readfirstlane(threadIdx.x >> 6);
  const int j0 = w * 6;
  const float4* p = (const float4*)(h1h + (size_t)(t + 1) * (HD * 64)) + lane;
  const float* r[6];
  float acc[6];
#pragma unroll
  for (int jj = 0; jj < 6; ++jj) {
    int j = j0 + jj; if (j > 21) j = 21;
    r[jj] = Wtag + (size_t)j * HD;
    acc[jj] = btag[j];
  }
#pragma unroll 2
  for (int c = 0; c < 128; ++c) {
    float4 h = p[(size_t)c * 64];
    int k = c * 4;
#pragma unroll
    for (int jj = 0; jj < 6; ++jj) {
      acc[jj] = fmaf(h.x, r[jj][k], acc[jj]);
      acc[jj] = fmaf(h.y, r[jj][k + 1], acc[jj]);
      acc[jj] = fmaf(h.z, r[jj][k + 2], acc[jj]);
      acc[jj] = fmaf(h.w, r[jj][k + 3], acc[jj]);
    }
  }
#pragma unroll
  for (int jj = 0; jj < 6; ++jj) {
    int j = j0 + jj;
    if (j < NTAG) feats[((size_t)t * NTAG + j) * 64 + lane] = acc[jj];
  }
}

// K5: Viterbi decode, one block per batch element, backpointers in LDS.
__global__ __launch_bounds__(64) void k5(const float* __restrict__ feats,
                                         const float* __restrict__ trans,
                                         const int* __restrict__ lengths,
                                         float* __restrict__ out) {
  const int b = blockIdx.x;
  const int j = threadIdx.x;
  __shared__ float tr[NTAG * NTAG];
  __shared__ float sc[NTAG];
  __shared__ float term[NTAG];
  __shared__ unsigned char bp[SS - 1][NTAG];
  for (int i = j; i < NTAG * NTAG; i += 64) tr[i] = trans[i];
  const int len = lengths[b];
  float score = 0.f;
  __syncthreads();
  if (j < NTAG) {
    score = feats[(size_t)j * 64 + b] + tr[j * NTAG + TSTART];
    sc[j] = score;
  }
  __syncthreads();
  for (int t = 1; t < len; ++t) {
    float best = -3.4e38f; int bi_ = 0;
    if (j < NTAG) {
#pragma unroll
      for (int i = 0; i < NTAG; ++i) {
        float c = sc[i] + tr[j * NTAG + i];
        if (c > best) { best = c; bi_ = i; }   // strict > keeps first max
      }
      score = best + feats[((size_t)t * NTAG + j) * 64 + b];
      bp[t - 1][j] = (unsigned char)bi_;
    }
    __syncthreads();
    if (j < NTAG) sc[j] = score;
    __syncthreads();
  }
  if (j < NTAG) term[j] = score + tr[TSTOP * NTAG + j];
  __syncthreads();
  if (j == 0) {
    float bs = term[0]; int bt = 0;
    for (int i = 1; i < NTAG; ++i) if (term[i] > bs) { bs = term[i]; bt = i; }
    out[b] = bs;
    int tag = bt;
    for (int t = SS - 1; t >= 1; --t) {
      out[64 + (size_t)b * SS + t] = (float)tag;
      if (t < len) tag = bp[t - 1][tag];
    }
    out[64 + (size_t)b * SS + 0] = (float)tag;
  }
}

extern "C" void kernel_launch(void* const* d_in, const int* in_sizes, int n_in,
                              void* d_out, int out_size, void* d_ws, size_t ws_size,
                              hipStream_t stream) {
  const int* sentence = (const int*)d_in[0];
  const int* lengths  = (const int*)d_in[1];
  const float* emb    = (const float*)d_in[2];
  const float* wih_f  = (const float*)d_in[3];
  const float* whh_f  = (const float*)d_in[4];
  const float* b_f    = (const float*)d_in[5];
  const float* wih_b  = (const float*)d_in[6];
  const float* whh_b  = (const float*)d_in[7];
  const float* b_b    = (const float*)d_in[8];
  const float* h10    = (const float*)d_in[9];
  const float* c10    = (const float*)d_in[10];
  const float* wihs   = (const float*)d_in[11];
  const float* whhs   = (const float*)d_in[12];
  const float* bs     = (const float*)d_in[13];
  const float* h20    = (const float*)d_in[14];
  const float* c20    = (const float*)d_in[15];
  const float* Wtag   = (const float*)d_in[16];
  const float* btag   = (const float*)d_in[17];
  const float* trans  = (const float*)d_in[18];
  float* ws = (float*)d_ws;
  float* out = (float*)d_out;
  int* barbase = (int*)(ws + OFF_BAR);

  // zero barrier state (ws is poisoned 0xAA before every call)
  hipMemsetAsync((void*)barbase, 0, BAR_INTS * sizeof(int), stream);

  k0<<<dim3(SS), dim3(256), 0, stream>>>(sentence, emb, ws + OFF_XT);

  K2A a2{ws + OFF_XT, ws + OFF_BI, wih_f, whh_f, b_f, wih_b, whh_b, b_b,
         h10, c10, lengths,
         ws + OFF_HF, ws + OFF_HB,
         barbase};
  k2<<<dim3(256), dim3(256), 0, stream>>>(a2);

  K4A a4{ws + OFF_BI, ws + OFF_H0R, ws + OFF_H1H, wihs, whhs, bs, h20, c20,
         barbase + 768};
  k4<<<dim3(256), dim3(512), 0, stream>>>(a4);

  k4b<<<dim3(SS), dim3(256), 0, stream>>>(ws + OFF_H1H, Wtag, btag, ws + OFF_FEATS);
  k5<<<dim3(BB), dim3(64), 0, stream>>>(ws + OFF_FEATS, trans, lengths, out);
}

// Round 6
// 17559.354 us; speedup vs baseline: 2.6839x; 1.4166x over previous
//
#include <hip/hip_runtime.h>
#include <cmath>

// ResLSTM+CRF on MI355X, fp32 vector-ALU implementation.
// R6: revert to R4-proven launch geometry (256 blocks, <=512 thr, 1 block/CU
// guaranteed -> spin barrier can never deadlock). Keep R5's LDS-weight idea
// within 48 KB static LDS:
//   k2: all 8 gate rows (x||h) in LDS (16 KB), 8 waves x 64-k slices.
//   k4: whh half (16 rows x 512 = 32 KB) in LDS for the h-waves; wih stays in
//       global (L1/L2-cached, ~32 KB/block working set). 2-stage part reduce.
// Cross-block recurrent arrays accessed only via coherence-point ops
// (relaxed agent atomic stores; global_load_dwordx4 sc0 sc1 + vmcnt).
// Centralized-release barrier (R4 layout, unchanged).

namespace {
constexpr int SS = 512;     // seq len
constexpr int BB = 64;      // batch
constexpr int EE = 256;     // embed dim
constexpr int HHd = 256;    // half hidden (bi-lstm)
constexpr int HD = 512;     // hidden (stack)
constexpr int NTAG = 22;
constexpr int TSTART = 20;
constexpr int TSTOP = 21;

// ws offsets (in floats)
constexpr size_t OFF_BI    = 0;                                      // [512][512][64] chunked (ordinary)
constexpr size_t OFF_H1H   = OFF_BI    + (size_t)SS * HD * BB;       // [513][512][64] chunked (coherent)
constexpr size_t OFF_XT    = OFF_H1H   + (size_t)(SS + 1) * HD * BB; // [512][256][64] chunked (ordinary)
constexpr size_t OFF_FEATS = OFF_XT    + (size_t)SS * EE * BB;       // [512][22][64]
constexpr size_t OFF_H0R   = OFF_FEATS + (size_t)SS * NTAG * BB;     // [2][512][64] chunked (coherent)
constexpr size_t OFF_HF    = OFF_H0R   + 2 * (size_t)HD * BB;        // [2][256][64] chunked (coherent)
constexpr size_t OFF_HB    = OFF_HF    + 2 * (size_t)HHd * BB;
constexpr size_t OFF_BAR   = OFF_HB    + 2 * (size_t)HHd * BB;       // barrier state (ints)
// barrier ints: k2 fwd flags@0(128) rel@160 ; k2 bwd flags@384(128) rel@544 ;
//               k4 flags@768(256) rel@1056
constexpr int BAR_INTS = 1152;
}

__device__ __forceinline__ int cidx(int k, int lane) {
  return ((k >> 2) << 8) + (lane << 2) + (k & 3);
}

// Coherence-point 16B load: bypasses (possibly stale) L1/L2, reads L3/mem.
__device__ __forceinline__ float4 cload4(const float4* p) {
  float4 r;
  asm volatile("global_load_dwordx4 %0, %1, off sc0 sc1" : "=v"(r) : "v"(p));
  return r;
}
__device__ __forceinline__ void vwait0() {
  asm volatile("s_waitcnt vmcnt(0)" ::: "memory");
}
// Coherence-point 4B store (write-through, no dirty line in local L2).
__device__ __forceinline__ void cstore(float* p, float v) {
  __hip_atomic_store(p, v, __ATOMIC_RELAXED, __HIP_MEMORY_SCOPE_AGENT);
}

// Centralized-release device barrier, no fences.
// Callers must vmcnt-drain their own coherent stores (vwait0) before entering.
template <int NBLK>
__device__ __forceinline__ void gbarC(int* flags, int* release, int bid, int epoch) {
  __syncthreads();
  if (threadIdx.x == 0) {
    __hip_atomic_store(flags + bid, epoch + 1, __ATOMIC_RELAXED, __HIP_MEMORY_SCOPE_AGENT);
  }
  if (bid == 0) {
    if (threadIdx.x < 64) {
      constexpr int PER = NBLK / 64;
      bool ok;
      do {
        ok = true;
#pragma unroll
        for (int i = 0; i < PER; ++i) {
          ok = ok && (__hip_atomic_load(flags + threadIdx.x * PER + i, __ATOMIC_RELAXED,
                                        __HIP_MEMORY_SCOPE_AGENT) > epoch);
        }
      } while (__any(!ok));
      if (threadIdx.x == 0) {
        __hip_atomic_store(release, epoch + 1, __ATOMIC_RELAXED, __HIP_MEMORY_SCOPE_AGENT);
      }
    }
  } else {
    if (threadIdx.x == 0) {
      while (__hip_atomic_load(release, __ATOMIC_RELAXED, __HIP_MEMORY_SCOPE_AGENT) <= epoch) {
        __builtin_amdgcn_s_sleep(1);
      }
    }
  }
  __syncthreads();
}

__device__ __forceinline__ float sigm(float x) { return 1.f / (1.f + expf(-x)); }
__device__ __forceinline__ float comp4(float4 v, int w) {
  return (w == 0) ? v.x : (w == 1) ? v.y : (w == 2) ? v.z : v.w;
}

// K0: gather embeddings, transpose to chunked [t][e-chunk][lane][4]
__global__ __launch_bounds__(256) void k0(const int* __restrict__ sent,
                                          const float* __restrict__ emb,
                                          float* __restrict__ xT) {
  const int t = blockIdx.x;
  const int lane = threadIdx.x & 63;
  const int w = __builtin_amdgcn_readfirstlane(threadIdx.x >> 6); // 0..3
  __shared__ float tile[64][65];
  __shared__ int rows[64];
  if (threadIdx.x < 64) rows[threadIdx.x] = sent[(size_t)threadIdx.x * SS + t];
  __syncthreads();
  float4* xT4 = (float4*)xT;
  for (int e0 = 0; e0 < EE; e0 += 64) {
    for (int bb = 0; bb < 16; ++bb) {
      int b = bb * 4 + w;
      tile[b][lane] = emb[(size_t)rows[b] * EE + e0 + lane];
    }
    __syncthreads();
    for (int r = 0; r < 4; ++r) {
      int ecl = w * 4 + r;
      int ec = (e0 >> 2) + ecl;
      float4 v = make_float4(tile[lane][ecl * 4 + 0], tile[lane][ecl * 4 + 1],
                             tile[lane][ecl * 4 + 2], tile[lane][ecl * 4 + 3]);
      xT4[((size_t)t * 64 + ec) * 64 + lane] = v;
    }
    __syncthreads();
  }
}

struct K2A {
  const float* xT; float* bi;
  const float* wih_f; const float* whh_f; const float* b_f;
  const float* wih_b; const float* whh_b; const float* b_b;
  const float* h10; const float* c10; const int* lengths;
  float* hf; float* hb;
  int* bar;
};

// K2: BiLSTM. 256 blocks x 512 thr (1 block/CU). Block (d = bid>>7, lb = bid&127)
// owns units {2lb, 2lb+1} (8 gate rows, r = g*2+ul). All 8 rows of z=[x;h] weights
// (8 x 512 floats = 16 KB) staged to LDS. 8 waves partition z into 64-k slices:
// w<4 -> x (xT, ordinary), w>=4 -> h (hbuf ring, coherent).
__global__ __launch_bounds__(512) void k2(K2A a) {
  const int lane = threadIdx.x & 63;
  const int w = __builtin_amdgcn_readfirstlane((int)threadIdx.x >> 6); // 0..7
  const int d = (int)blockIdx.x >> 7;
  const int lb = (int)blockIdx.x & 127;
  int* flags = a.bar + d * 384;
  int* release = a.bar + d * 384 + 160;
  const int u0 = lb * 2;
  const float* wih = d ? a.wih_b : a.wih_f;
  const float* whh = d ? a.whh_b : a.whh_f;
  const float* bias = d ? a.b_b : a.b_f;
  float* hbuf = d ? a.hb : a.hf;

  __shared__ float lw[8 * 512];          // 16 KB: [r][z-k], r = g*2+ul
  __shared__ float4 part[8][2][64];      // 16 KB

  // stage weights: 1024 float4s, 2 per thread
#pragma unroll
  for (int i = 0; i < 2; ++i) {
    int f4 = i * 512 + (int)threadIdx.x; // 0..1023
    int r = f4 >> 7;                     // 128 f4 per row
    int kk = (f4 & 127) * 4;
    int g = r >> 1, ul = r & 1;
    int grow = g * HHd + u0 + ul;
    float4 v = (kk < 256) ? *(const float4*)(wih + (size_t)grow * 256 + kk)
                          : *(const float4*)(whh + (size_t)grow * 256 + (kk - 256));
    *(float4*)(lw + r * 512 + kk) = v;
  }

  const int len = a.lengths[lane];
  float c_st = 0.f, h_old = 0.f;
  if (w < 2) {
    int u = u0 + w;
    h_old = a.h10[d * 256 + u];
    c_st = a.c10[d * 256 + u];
    cstore(&hbuf[cidx(u, lane)], h_old);
    vwait0();
  }
  int ep = 0;
  gbarC<128>(flags, release, lb, ep); ep++;   // entry __syncthreads orders staging

  const int ks = w * 64;                 // z-slice start (0..448)
  const bool hpart = (w >= 4);
  const float4* lw4 = (const float4*)lw;
  int buf = 0;
  for (int step = 0; step < SS; ++step) {
    const int t = d ? (SS - 1 - step) : step;
    const float* actbase = hpart ? (hbuf + (size_t)buf * (HHd * 64))
                                 : (a.xT + (size_t)t * (EE * 64));
    const int ksl = hpart ? (ks - 256) : ks;
    const float4* p = (const float4*)actbase + (size_t)(ksl >> 2) * 64 + lane;
    float4 va[16];
    if (hpart) {
#pragma unroll
      for (int c = 0; c < 16; ++c) va[c] = cload4(p + (size_t)c * 64);
      vwait0();
    } else {
#pragma unroll
      for (int c = 0; c < 16; ++c) va[c] = p[(size_t)c * 64];
    }
    float acc[8] = {0, 0, 0, 0, 0, 0, 0, 0};
#pragma unroll
    for (int c = 0; c < 16; ++c) {
      float4 h = va[c];
#pragma unroll
      for (int r = 0; r < 8; ++r) {
        float4 wv = lw4[r * 128 + (ks >> 2) + c];   // broadcast ds_read_b128
        acc[r] = fmaf(h.x, wv.x, acc[r]);
        acc[r] = fmaf(h.y, wv.y, acc[r]);
        acc[r] = fmaf(h.z, wv.z, acc[r]);
        acc[r] = fmaf(h.w, wv.w, acc[r]);
      }
    }
    part[w][0][lane] = make_float4(acc[0], acc[1], acc[2], acc[3]);
    part[w][1][lane] = make_float4(acc[4], acc[5], acc[6], acc[7]);
    __syncthreads();
    if (w < 2) {
      // acc rows: [0..3] = {i.u0,i.u1,f.u0,f.u1}, [4..7] = {g.u0,g.u1,o.u0,o.u1}
      float qi = 0.f, qf = 0.f, qg = 0.f, qo = 0.f;
#pragma unroll
      for (int wv = 0; wv < 8; ++wv) {
        float4 p0 = part[wv][0][lane], p1 = part[wv][1][lane];
        qi += comp4(p0, w);  qf += comp4(p0, 2 + w);
        qg += comp4(p1, w);  qo += comp4(p1, 2 + w);
      }
      const int u = u0 + w;
      float gi = qi + bias[u];
      float gf = qf + bias[256 + u];
      float gg = qg + bias[512 + u];
      float go = qo + bias[768 + u];
      float i_ = sigm(gi), f_ = sigm(gf), o_ = sigm(go);
      float gn = tanhf(gg);
      float c2 = f_ * c_st + i_ * gn;
      float h2 = o_ * tanhf(c2);
      const bool m = (t < len);
      h2 = m ? h2 : h_old;
      c_st = m ? c2 : c_st;
      h_old = h2;
      cstore(&hbuf[(size_t)(buf ^ 1) * (HHd * 64) + cidx(u, lane)], h2);
      a.bi[(size_t)t * (HD * 64) + cidx(d * 256 + u, lane)] = m ? h2 : 0.f; // ordinary
      vwait0();
    }
    buf ^= 1;
    gbarC<128>(flags, release, lb, ep); ep++;
  }
}

struct K4A {
  const float* bi; float* h0r; float* h1h;
  const float* wihs; const float* whhs; const float* bs;
  const float* h20; const float* c20;
  int* bar;
};

// K4: 2-layer stack LSTM, software-pipelined (super-step t: layer0 t, layer1 t-1).
// 256 blocks x 512 thr (R4-proven, 1 block/CU). Block (layer = bid>>7, lb = bid&127)
// owns units 4lb..4lb+3 (16 gate rows, r = g*4+ul). whh rows (16x512 = 32 KB) in LDS
// for the h-waves; wih rows read from global (cached) by the x-waves.
// 8 waves partition z: w<4 -> x 128-k slices, w>=4 -> h 128-k slices (coherent).
// 2-stage cross-wave reduction in 16 KB of LDS.
__global__ __launch_bounds__(512) void k4(K4A a) {
  const int lane = threadIdx.x & 63;
  const int w = __builtin_amdgcn_readfirstlane((int)threadIdx.x >> 6);  // 0..7
  const int layer = (int)blockIdx.x >> 7;
  const int lb = (int)blockIdx.x & 127;
  const int u0 = lb * 4;
  const float* wih = a.wihs + (size_t)layer * (2048 * 512);
  const float* whh = a.whhs + (size_t)layer * (2048 * 512);

  __shared__ float lwh[16 * 512];        // 32 KB: whh rows, r = g*4+ul
  __shared__ float part[4][16][64];      // 16 KB

  // stage whh: 2048 float4s, 4 per thread
#pragma unroll
  for (int i = 0; i < 4; ++i) {
    int f4 = i * 512 + (int)threadIdx.x; // 0..2047
    int r = f4 >> 7;                     // 128 f4 per row
    int kk = (f4 & 127) * 4;
    int g = r >> 2, ul = r & 3;
    int grow = g * HD + u0 + ul;
    *(float4*)(lwh + r * 512 + kk) = *(const float4*)(whh + (size_t)grow * 512 + kk);
  }

  // x-wave global weight row pointers (wave-uniform -> SGPRs)
  const int ks = (w & 3) * 128;
  const float* wr[16];
#pragma unroll
  for (int g = 0; g < 4; ++g)
#pragma unroll
    for (int ul = 0; ul < 4; ++ul)
      wr[g * 4 + ul] = wih + (size_t)(g * HD + u0 + ul) * HD + ks;

  float c_st = 0.f;
  if (w < 4) {
    const int u = u0 + w;
    c_st = a.c20[layer * 512 + u];
    float h0i = a.h20[layer * 512 + u];
    if (layer == 0) cstore(&a.h0r[cidx(u, lane)], h0i);
    else            cstore(&a.h1h[cidx(u, lane)], h0i);
    vwait0();
  }
  int ep = 0;
  gbarC<256>(a.bar, a.bar + 288, blockIdx.x, ep); ep++;   // orders staging too

  const bool hpart = (w >= 4);
  const float4* lwh4 = (const float4*)lwh;
  for (int t = 0; t <= SS; ++t) {
    const bool active = (layer == 0) ? (t < SS) : (t >= 1);
    float acc[16] = {0, 0, 0, 0, 0, 0, 0, 0, 0, 0, 0, 0, 0, 0, 0, 0};
    if (active) {
      const float* actbase;
      bool coh;
      if (layer == 0) {
        actbase = hpart ? (a.h0r + (size_t)(t & 1) * (HD * 64))
                        : (a.bi + (size_t)t * (HD * 64));
        coh = hpart;
      } else {
        actbase = hpart ? (a.h1h + (size_t)(t - 1) * (HD * 64))
                        : (a.h0r + (size_t)(t & 1) * (HD * 64));
        coh = true;
      }
      const float4* p = (const float4*)actbase + (size_t)(ks >> 2) * 64 + lane;
#pragma unroll
      for (int gseg = 0; gseg < 2; ++gseg) {
        float4 va[16];
        const float4* pg = p + (size_t)gseg * 16 * 64;
        if (coh) {
#pragma unroll
          for (int c = 0; c < 16; ++c) va[c] = cload4(pg + (size_t)c * 64);
          vwait0();
        } else {
#pragma unroll
          for (int c = 0; c < 16; ++c) va[c] = pg[(size_t)c * 64];
        }
#pragma unroll
        for (int c = 0; c < 16; ++c) {
          float4 h = va[c];
          const int kc = gseg * 16 + c;        // f4 chunk within 128-k slice
          if (hpart) {
#pragma unroll
            for (int r = 0; r < 16; ++r) {
              float4 wv = lwh4[r * 128 + (ks >> 2) + kc];   // broadcast
              acc[r] = fmaf(h.x, wv.x, acc[r]);
              acc[r] = fmaf(h.y, wv.y, acc[r]);
              acc[r] = fmaf(h.z, wv.z, acc[r]);
              acc[r] = fmaf(h.w, wv.w, acc[r]);
            }
          } else {
            const int k = kc * 4;
#pragma unroll
            for (int r = 0; r < 16; ++r) {
              float4 wv = *(const float4*)(wr[r] + k);      // cached global
              acc[r] = fmaf(h.x, wv.x, acc[r]);
              acc[r] = fmaf(h.y, wv.y, acc[r]);
              acc[r] = fmaf(h.z, wv.z, acc[r]);
              acc[r] = fmaf(h.w, wv.w, acc[r]);
            }
          }
        }
      }
    }
    // 2-stage cross-wave reduction: waves 0-3 write, waves 4-7 add.
    if (w < 4) {
#pragma unroll
      for (int r = 0; r < 16; ++r) part[w][r][lane] = acc[r];
    }
    __syncthreads();
    if (w >= 4) {
#pragma unroll
      for (int r = 0; r < 16; ++r) part[w - 4][r][lane] += acc[r];
    }
    __syncthreads();
    if (active && w < 4) {
      // unit u = u0 + w; gates g: row r = g*4 + w, summed over 4 slots
      float q[4];
#pragma unroll
      for (int g = 0; g < 4; ++g) {
        float s = 0.f;
#pragma unroll
        for (int sl = 0; sl < 4; ++sl) s += part[sl][g * 4 + w][lane];
        q[g] = s;
      }
      const int u = u0 + w;
      const float* bsl = a.bs + (size_t)layer * 2048;
      float gi = q[0] + bsl[u];
      float gf = q[1] + bsl[512 + u];
      float gg = q[2] + bsl[1024 + u];
      float go = q[3] + bsl[1536 + u];
      float i_ = sigm(gi), f_ = sigm(gf), o_ = sigm(go);
      float gn = tanhf(gg);
      float c2 = f_ * c_st + i_ * gn;
      float h2 = o_ * tanhf(c2);
      c_st = c2;
      if (layer == 0)
        cstore(&a.h0r[(size_t)((t + 1) & 1) * (HD * 64) + cidx(u, lane)], h2);
      else
        cstore(&a.h1h[(size_t)t * (HD * 64) + cidx(u, lane)], h2);
      vwait0();
    }
    gbarC<256>(a.bar, a.bar + 288, blockIdx.x, ep); ep++;
  }
}

// K4b: feats[t][j][b] = h1(t) . W_tag[j] + b_tag[j]
__global__ __launch_bounds__(256) void k4b(const float* __restrict__ h1h,
                                           const float* __restrict__ Wtag,
                                           const float* __restrict__ btag,
                                           float* __restrict__ feats) {
  const int t = blockIdx.x;
  const int lane = threadIdx.x & 63;
  const int w = __builtin_amdgcn_readfirstlane(threadIdx.x >> 6);
  const int j0 = w * 6;
  const float4* p = (const float4*)(h1h + (size_t)(t + 1) * (HD * 64)) + lane;
  const float* r[6];
  float acc[6];
#pragma unroll
  for (int jj = 0; jj < 6; ++jj) {
    int j = j0 + jj; if (j > 21) j = 21;
    r[jj] = Wtag + (size_t)j * HD;
    acc[jj] = btag[j];
  }
#pragma unroll 2
  for (int c = 0; c < 128; ++c) {
    float4 h = p[(size_t)c * 64];
    int k = c * 4;
#pragma unroll
    for (int jj = 0; jj < 6; ++jj) {
      acc[jj] = fmaf(h.x, r[jj][k], acc[jj]);
      acc[jj] = fmaf(h.y, r[jj][k + 1], acc[jj]);
      acc[jj] = fmaf(h.z, r[jj][k + 2], acc[jj]);
      acc[jj] = fmaf(h.w, r[jj][k + 3], acc[jj]);
    }
  }
#pragma unroll
  for (int jj = 0; jj < 6; ++jj) {
    int j = j0 + jj;
    if (j < NTAG) feats[((size_t)t * NTAG + j) * 64 + lane] = acc[jj];
  }
}

// K5: Viterbi decode, one block per batch element, backpointers in LDS.
__global__ __launch_bounds__(64) void k5(const float* __restrict__ feats,
                                         const float* __restrict__ trans,
                                         const int* __restrict__ lengths,
                                         float* __restrict__ out) {
  const int b = blockIdx.x;
  const int j = threadIdx.x;
  __shared__ float tr[NTAG * NTAG];
  __shared__ float sc[NTAG];
  __shared__ float term[NTAG];
  __shared__ unsigned char bp[SS - 1][NTAG];
  for (int i = j; i < NTAG * NTAG; i += 64) tr[i] = trans[i];
  const int len = lengths[b];
  float score = 0.f;
  __syncthreads();
  if (j < NTAG) {
    score = feats[(size_t)j * 64 + b] + tr[j * NTAG + TSTART];
    sc[j] = score;
  }
  __syncthreads();
  for (int t = 1; t < len; ++t) {
    float best = -3.4e38f; int bi_ = 0;
    if (j < NTAG) {
#pragma unroll
      for (int i = 0; i < NTAG; ++i) {
        float c = sc[i] + tr[j * NTAG + i];
        if (c > best) { best = c; bi_ = i; }   // strict > keeps first max
      }
      score = best + feats[((size_t)t * NTAG + j) * 64 + b];
      bp[t - 1][j] = (unsigned char)bi_;
    }
    __syncthreads();
    if (j < NTAG) sc[j] = score;
    __syncthreads();
  }
  if (j < NTAG) term[j] = score + tr[TSTOP * NTAG + j];
  __syncthreads();
  if (j == 0) {
    float bs = term[0]; int bt = 0;
    for (int i = 1; i < NTAG; ++i) if (term[i] > bs) { bs = term[i]; bt = i; }
    out[b] = bs;
    int tag = bt;
    for (int t = SS - 1; t >= 1; --t) {
      out[64 + (size_t)b * SS + t] = (float)tag;
      if (t < len) tag = bp[t - 1][tag];
    }
    out[64 + (size_t)b * SS + 0] = (float)tag;
  }
}

extern "C" void kernel_launch(void* const* d_in, const int* in_sizes, int n_in,
                              void* d_out, int out_size, void* d_ws, size_t ws_size,
                              hipStream_t stream) {
  const int* sentence = (const int*)d_in[0];
  const int* lengths  = (const int*)d_in[1];
  const float* emb    = (const float*)d_in[2];
  const float* wih_f  = (const float*)d_in[3];
  const float* whh_f  = (const float*)d_in[4];
  const float* b_f    = (const float*)d_in[5];
  const float* wih_b  = (const float*)d_in[6];
  const float* whh_b  = (const float*)d_in[7];
  const float* b_b    = (const float*)d_in[8];
  const float* h10    = (const float*)d_in[9];
  const float* c10    = (const float*)d_in[10];
  const float* wihs   = (const float*)d_in[11];
  const float* whhs   = (const float*)d_in[12];
  const float* bs     = (const float*)d_in[13];
  const float* h20    = (const float*)d_in[14];
  const float* c20    = (const float*)d_in[15];
  const float* Wtag   = (const float*)d_in[16];
  const float* btag   = (const float*)d_in[17];
  const float* trans  = (const float*)d_in[18];
  float* ws = (float*)d_ws;
  float* out = (float*)d_out;
  int* barbase = (int*)(ws + OFF_BAR);

  // zero barrier state (ws is poisoned 0xAA before every call)
  hipMemsetAsync((void*)barbase, 0, BAR_INTS * sizeof(int), stream);

  k0<<<dim3(SS), dim3(256), 0, stream>>>(sentence, emb, ws + OFF_XT);

  K2A a2{ws + OFF_XT, ws + OFF_BI, wih_f, whh_f, b_f, wih_b, whh_b, b_b,
         h10, c10, lengths,
         ws + OFF_HF, ws + OFF_HB,
         barbase};
  k2<<<dim3(256), dim3(512), 0, stream>>>(a2);

  K4A a4{ws + OFF_BI, ws + OFF_H0R, ws + OFF_H1H, wihs, whhs, bs, h20, c20,
         barbase + 768};
  k4<<<dim3(256), dim3(512), 0, stream>>>(a4);

  k4b<<<dim3(SS), dim3(256), 0, stream>>>(ws + OFF_H1H, Wtag, btag, ws + OFF_FEATS);
  k5<<<dim3(BB), dim3(64), 0, stream>>>(ws + OFF_FEATS, trans, lengths, out);
}